// Round 7
// baseline (516.863 us; speedup 1.0000x reference)
//
#include <hip/hip_runtime.h>
#include <cmath>

#define NN 100000
#define NE 1600000
#define FIN 128
#define HID 128
#define NCLS 40

#define BSHIFT 5
#define BMASK 31
#define NB_BK (NN >> BSHIFT)   // 3125 buckets of exactly 32 nodes (100000 = 3125*32)

// ---- packed bf16 helpers (RNE) ----
__device__ __forceinline__ unsigned pk_bf16(float a, float b) {
    unsigned ua = __float_as_uint(a);
    unsigned ub = __float_as_uint(b);
    ua += 0x7FFFu + ((ua >> 16) & 1u);
    ub += 0x7FFFu + ((ub >> 16) & 1u);
    return (ua >> 16) | (ub & 0xFFFF0000u);
}
__device__ __forceinline__ float2 upk_bf16(unsigned u) {
    return make_float2(__uint_as_float(u << 16), __uint_as_float(u & 0xFFFF0000u));
}

// ---------------- CSR build v2: bucket-staged, low write-amplification ----------------

// bucket histogram via LDS (98 blocks x 16384 edges), flush nonzero counts
__global__ __launch_bounds__(256) void bhist_kernel(const int* __restrict__ dst,
                                                    int* __restrict__ bcnt) {
    __shared__ int h[NB_BK];
    int tid = threadIdx.x;
    for (int i = tid; i < NB_BK; i += 256) h[i] = 0;
    __syncthreads();
    int base = blockIdx.x * 16384;
#pragma unroll 4
    for (int k = 0; k < 64; ++k) {
        int e = base + k * 256 + tid;
        if (e < NE) atomicAdd(&h[dst[e] >> BSHIFT], 1);
    }
    __syncthreads();
    for (int i = tid; i < NB_BK; i += 256) {
        int v = h[i];
        if (v) atomicAdd(&bcnt[i], v);
    }
}

// single-block exclusive scan of bcnt[NB_BK] -> bbase[NB_BK+1]
__global__ __launch_bounds__(1024) void bscan_kernel(const int* __restrict__ bcnt,
                                                     int* __restrict__ bbase) {
    __shared__ int tsum[1024];
    int tid = threadIdx.x;
    int base = tid * 4;
    int v0 = 0, v1 = 0, v2 = 0, v3 = 0;
    if (base + 0 < NB_BK) v0 = bcnt[base + 0];
    if (base + 1 < NB_BK) v1 = bcnt[base + 1];
    if (base + 2 < NB_BK) v2 = bcnt[base + 2];
    if (base + 3 < NB_BK) v3 = bcnt[base + 3];
    int s = v0 + v1 + v2 + v3;
    tsum[tid] = s;
    __syncthreads();
    for (int off = 1; off < 1024; off <<= 1) {
        int add = (tid >= off) ? tsum[tid - off] : 0;
        __syncthreads();
        tsum[tid] += add;
        __syncthreads();
    }
    int ex = tsum[tid] - s;
    if (base + 0 < NB_BK) bbase[base + 0] = ex;
    ex += v0;
    if (base + 1 < NB_BK) bbase[base + 1] = ex;
    ex += v1;
    if (base + 2 < NB_BK) bbase[base + 2] = ex;
    ex += v2;
    if (base + 3 < NB_BK) bbase[base + 3] = ex;
    if (tid == 1023) bbase[NB_BK] = tsum[1023];  // == NE
}

// pass 1: stage edges into bucket regions, packed (src<<5)|dst_local
__global__ __launch_bounds__(256) void stage_kernel(const int* __restrict__ src,
                                                    const int* __restrict__ dst,
                                                    const int* __restrict__ bbase,
                                                    int* __restrict__ bcur,
                                                    unsigned* __restrict__ staging) {
    int e = blockIdx.x * blockDim.x + threadIdx.x;
    if (e < NE) {
        int d = dst[e];
        int b = d >> BSHIFT;
        int pos = bbase[b] + atomicAdd(&bcur[b], 1);
        staging[pos] = ((unsigned)src[e] << BSHIFT) | (unsigned)(d & BMASK);
    }
}

// pass 2: per-bucket build: deg/row_ptr/dinv + locality-friendly col scatter
__global__ __launch_bounds__(256) void build_kernel(const unsigned* __restrict__ staging,
                                                    const int* __restrict__ bbase,
                                                    int* __restrict__ row_ptr,
                                                    float* __restrict__ dinv,
                                                    int* __restrict__ col) {
    __shared__ int ldeg[32];
    __shared__ int lofs[32];
    __shared__ int cur[32];
    int tid = threadIdx.x;
    int b = blockIdx.x;
    int nbase = b << BSHIFT;
    int ebeg = bbase[b], eend = bbase[b + 1];
    int cnt = eend - ebeg;
    if (tid < 32) ldeg[tid] = 0;
    __syncthreads();
    for (int i = tid; i < cnt; i += 256) atomicAdd(&ldeg[staging[ebeg + i] & BMASK], 1);
    __syncthreads();
    if (tid == 0) {
        int s = 0;
        for (int j = 0; j < 32; ++j) { lofs[j] = s; s += ldeg[j]; }
    }
    __syncthreads();
    if (tid < 32) {
        row_ptr[nbase + tid] = ebeg + lofs[tid];
        dinv[nbase + tid] = rsqrtf((float)(ldeg[tid] + 1));  // +1 self-loop
        cur[tid] = lofs[tid];
    }
    if (b == NB_BK - 1 && tid == 0) row_ptr[NN] = NE;
    __syncthreads();
    for (int i = tid; i < cnt; i += 256) {
        unsigned u = staging[ebeg + i];
        int pos = atomicAdd(&cur[u & BMASK], 1);
        col[ebeg + pos] = (int)(u >> BSHIFT);
    }
}

// ---------------- GEMM1: hsb = bf16((x @ W1) * dinv[row]) ----------------
__global__ __launch_bounds__(256) void gemm1_kernel(const float* __restrict__ x,
                                                    const float* __restrict__ W1,
                                                    const float* __restrict__ dinv,
                                                    unsigned* __restrict__ hsb) {
    __shared__ float wlds[FIN][HID];   // 64KB, [k][c]
    __shared__ float xlds[32][FIN];    // 16KB, [r][k]
    int tid = threadIdx.x;
    for (int i = tid; i < FIN * HID; i += 256) wlds[i / HID][i % HID] = W1[i];
    int ct = tid & 31;        // c0 = 4*ct
    int rt = tid >> 5;        // r0 = 4*rt (8 tiles -> 32 rows)
    int c0 = ct * 4;
    int nt = (NN + 31) / 32;
    for (int t = blockIdx.x; t < nt; t += gridDim.x) {
        int rowbase = t * 32;
        __syncthreads();
        for (int i = tid; i < 32 * (FIN / 4); i += 256) {
            int r = i / (FIN / 4);
            int k4 = i % (FIN / 4);
            int row = rowbase + r;
            float4 v = (row < NN) ? ((const float4*)x)[(size_t)row * (FIN / 4) + k4]
                                  : make_float4(0.f, 0.f, 0.f, 0.f);
            ((float4*)&xlds[r][0])[k4] = v;
        }
        __syncthreads();
        float acc[4][4];
#pragma unroll
        for (int a = 0; a < 4; ++a)
#pragma unroll
            for (int b = 0; b < 4; ++b) acc[a][b] = 0.f;
        for (int k = 0; k < FIN; k += 4) {
            float4 xv[4], wv[4];
#pragma unroll
            for (int a = 0; a < 4; ++a) xv[a] = *(const float4*)&xlds[rt * 4 + a][k];
#pragma unroll
            for (int kk = 0; kk < 4; ++kk) wv[kk] = *(const float4*)&wlds[k + kk][c0];
#pragma unroll
            for (int kk = 0; kk < 4; ++kk) {
                float4 w = wv[kk];
#pragma unroll
                for (int a = 0; a < 4; ++a) {
                    float xs = ((float*)&xv[a])[kk];
                    acc[a][0] = fmaf(xs, w.x, acc[a][0]);
                    acc[a][1] = fmaf(xs, w.y, acc[a][1]);
                    acc[a][2] = fmaf(xs, w.z, acc[a][2]);
                    acc[a][3] = fmaf(xs, w.w, acc[a][3]);
                }
            }
        }
#pragma unroll
        for (int a = 0; a < 4; ++a) {
            int row = rowbase + rt * 4 + a;
            if (row < NN) {
                float dv = dinv[row];
                uint2 o = make_uint2(pk_bf16(acc[a][0] * dv, acc[a][1] * dv),
                                     pk_bf16(acc[a][2] * dv, acc[a][3] * dv));
                *(uint2*)(hsb + (size_t)row * 64 + ct * 2) = o;
            }
        }
    }
}

// ---------------- agg1: h1b = bf16(relu(dinv[i]*(hs[i] + sum_nbr hs) + b1)) ----------------
__global__ __launch_bounds__(256) void agg1_kernel(const unsigned* __restrict__ hsb,
                                                   const int* __restrict__ row_ptr,
                                                   const int* __restrict__ col,
                                                   const float* __restrict__ dinv,
                                                   const float* __restrict__ b1,
                                                   unsigned* __restrict__ h1b) {
    int wave = (blockIdx.x * blockDim.x + threadIdx.x) >> 6;
    int lane = threadIdx.x & 63;
    int nwaves = (gridDim.x * blockDim.x) >> 6;
    float2 bb = ((const float2*)b1)[lane];
    for (int i = wave; i < NN; i += nwaves) {
        float2 t = upk_bf16(hsb[(size_t)i * 64 + lane]);  // self term
        float ax = t.x, ay = t.y;
        int e = row_ptr[i], s1 = row_ptr[i + 1];
        for (; e + 4 <= s1; e += 4) {
            int sa = col[e + 0], sb = col[e + 1], sc = col[e + 2], sd = col[e + 3];
            unsigned ua = hsb[(size_t)sa * 64 + lane];
            unsigned ub = hsb[(size_t)sb * 64 + lane];
            unsigned uc = hsb[(size_t)sc * 64 + lane];
            unsigned ud = hsb[(size_t)sd * 64 + lane];
            float2 va = upk_bf16(ua), vb = upk_bf16(ub), vc = upk_bf16(uc), vd = upk_bf16(ud);
            ax += va.x + vb.x + vc.x + vd.x;
            ay += va.y + vb.y + vc.y + vd.y;
        }
        for (; e < s1; ++e) {
            float2 v = upk_bf16(hsb[(size_t)col[e] * 64 + lane]);
            ax += v.x;
            ay += v.y;
        }
        float dv = dinv[i];
        float ox = fmaxf(fmaf(ax, dv, bb.x), 0.f);
        float oy = fmaxf(fmaf(ay, dv, bb.y), 0.f);
        h1b[(size_t)i * 64 + lane] = pk_bf16(ox, oy);
    }
}

// ---------------- GEMM2: hs2b = bf16((h1 @ W2) * dinv[row]) ----------------
__global__ __launch_bounds__(256) void gemm2_kernel(const unsigned* __restrict__ h1b,
                                                    const float* __restrict__ W2,
                                                    const float* __restrict__ dinv,
                                                    unsigned* __restrict__ hs2b) {
    __shared__ float wlds[HID][64];   // 32KB zero-padded
    __shared__ float xlds[64][HID];   // 32KB
    int tid = threadIdx.x;
    for (int i = tid; i < HID * 64; i += 256) {
        int k = i / 64, c = i % 64;
        wlds[k][c] = (c < NCLS) ? W2[k * NCLS + c] : 0.f;
    }
    int ct = tid & 15;   // c0 = 4*ct (0..60)
    int rt = tid >> 4;   // 0..15 -> 64 rows
    int c0 = ct * 4;
    int nt = (NN + 63) / 64;
    for (int t = blockIdx.x; t < nt; t += gridDim.x) {
        int rowbase = t * 64;
        __syncthreads();
        // stage h1 (packed bf16) -> f32 LDS
        for (int i = tid; i < 64 * 16; i += 256) {
            int r = i >> 4, q = i & 15;
            int row = rowbase + r;
            uint4 u = (row < NN) ? ((const uint4*)h1b)[(size_t)row * 16 + q]
                                 : make_uint4(0, 0, 0, 0);
            float2 f0 = upk_bf16(u.x), f1 = upk_bf16(u.y);
            float2 f2 = upk_bf16(u.z), f3 = upk_bf16(u.w);
            float* dp = &xlds[r][q * 8];
            ((float4*)dp)[0] = make_float4(f0.x, f0.y, f1.x, f1.y);
            ((float4*)dp)[1] = make_float4(f2.x, f2.y, f3.x, f3.y);
        }
        __syncthreads();
        float acc[4][4];
#pragma unroll
        for (int a = 0; a < 4; ++a)
#pragma unroll
            for (int b = 0; b < 4; ++b) acc[a][b] = 0.f;
        for (int k = 0; k < HID; k += 4) {
            float4 xv[4], wv[4];
#pragma unroll
            for (int a = 0; a < 4; ++a) xv[a] = *(const float4*)&xlds[rt * 4 + a][k];
#pragma unroll
            for (int kk = 0; kk < 4; ++kk) wv[kk] = *(const float4*)&wlds[k + kk][c0];
#pragma unroll
            for (int kk = 0; kk < 4; ++kk) {
                float4 w = wv[kk];
#pragma unroll
                for (int a = 0; a < 4; ++a) {
                    float xs = ((float*)&xv[a])[kk];
                    acc[a][0] = fmaf(xs, w.x, acc[a][0]);
                    acc[a][1] = fmaf(xs, w.y, acc[a][1]);
                    acc[a][2] = fmaf(xs, w.z, acc[a][2]);
                    acc[a][3] = fmaf(xs, w.w, acc[a][3]);
                }
            }
        }
        if (c0 < NCLS) {
#pragma unroll
            for (int a = 0; a < 4; ++a) {
                int row = rowbase + rt * 4 + a;
                if (row < NN) {
                    float dv = dinv[row];
                    uint2 o = make_uint2(pk_bf16(acc[a][0] * dv, acc[a][1] * dv),
                                         pk_bf16(acc[a][2] * dv, acc[a][3] * dv));
                    *(uint2*)(hs2b + (size_t)row * 20 + ct * 2) = o;
                }
            }
        }
    }
}

// ---------------- agg2 + bias + log_softmax ----------------
__global__ __launch_bounds__(256) void agg2_kernel(const unsigned* __restrict__ hs2b,
                                                   const int* __restrict__ row_ptr,
                                                   const int* __restrict__ col,
                                                   const float* __restrict__ dinv,
                                                   const float* __restrict__ b2,
                                                   float* __restrict__ out) {
    int wave = (blockIdx.x * blockDim.x + threadIdx.x) >> 6;
    int lane = threadIdx.x & 63;
    int nwaves = (gridDim.x * blockDim.x) >> 6;
    bool act = lane < (NCLS / 2);
    float2 bb = act ? ((const float2*)b2)[lane] : make_float2(0.f, 0.f);
    for (int i = wave; i < NN; i += nwaves) {
        float ax = 0.f, ay = 0.f;
        if (act) {
            float2 t = upk_bf16(hs2b[(size_t)i * 20 + lane]);  // self term
            ax = t.x; ay = t.y;
        }
        int e = row_ptr[i], s1 = row_ptr[i + 1];
        for (; e + 4 <= s1; e += 4) {
            int sa = col[e + 0], sb = col[e + 1], sc = col[e + 2], sd = col[e + 3];
            if (act) {
                float2 va = upk_bf16(hs2b[(size_t)sa * 20 + lane]);
                float2 vb = upk_bf16(hs2b[(size_t)sb * 20 + lane]);
                float2 vc = upk_bf16(hs2b[(size_t)sc * 20 + lane]);
                float2 vd = upk_bf16(hs2b[(size_t)sd * 20 + lane]);
                ax += va.x + vb.x + vc.x + vd.x;
                ay += va.y + vb.y + vc.y + vd.y;
            }
        }
        for (; e < s1; ++e) {
            int s = col[e];
            if (act) {
                float2 v = upk_bf16(hs2b[(size_t)s * 20 + lane]);
                ax += v.x;
                ay += v.y;
            }
        }
        float dv = dinv[i];
        float lx = fmaf(ax, dv, bb.x);
        float ly = fmaf(ay, dv, bb.y);
        float m = act ? fmaxf(lx, ly) : -INFINITY;
#pragma unroll
        for (int off = 32; off; off >>= 1) m = fmaxf(m, __shfl_xor(m, off));
        float ssum = act ? (expf(lx - m) + expf(ly - m)) : 0.f;
#pragma unroll
        for (int off = 32; off; off >>= 1) ssum += __shfl_xor(ssum, off);
        float ls = logf(ssum);
        if (act) {
            float2 o = make_float2(lx - m - ls, ly - m - ls);
            ((float2*)(out + (size_t)i * NCLS))[lane] = o;
        }
    }
}

extern "C" void kernel_launch(void* const* d_in, const int* in_sizes, int n_in,
                              void* d_out, int out_size, void* d_ws, size_t ws_size,
                              hipStream_t stream) {
    const float* x = (const float*)d_in[0];
    const int* edge_index = (const int*)d_in[1];
    const float* W1 = (const float*)d_in[2];
    const float* b1 = (const float*)d_in[3];
    const float* W2 = (const float*)d_in[4];
    const float* b2 = (const float*)d_in[5];
    float* out = (float*)d_out;
    const int* src = edge_index;          // edge_index[0]
    const int* dst = edge_index + NE;     // edge_index[1]

    char* ws = (char*)d_ws;
    size_t off = 0;
    auto alloc = [&](size_t bytes) -> void* {
        void* p = (void*)(ws + off);
        off += (bytes + 255) & ~(size_t)255;
        return p;
    };
    int* bcnt = (int*)alloc((size_t)NB_BK * 4);
    int* bbase = (int*)alloc((size_t)(NB_BK + 1) * 4);
    int* bcur = (int*)alloc((size_t)NB_BK * 4);
    int* row_ptr = (int*)alloc((size_t)(NN + 1) * 4);
    int* col = (int*)alloc((size_t)NE * 4);
    float* dinv = (float*)alloc((size_t)NN * 4);
    unsigned* hsb = (unsigned*)alloc((size_t)NN * 64 * 4);   // bf16x2 packed [NN][64]
    unsigned* h1b = (unsigned*)alloc((size_t)NN * 64 * 4);   // bf16x2 packed [NN][64]
    unsigned* hs2b = (unsigned*)alloc((size_t)NN * 20 * 4);  // bf16x2 packed [NN][20]
    unsigned* staging = h1b;  // alias: staging dead before agg1 writes h1b

    hipMemsetAsync(bcnt, 0, (size_t)NB_BK * 4, stream);
    hipMemsetAsync(bcur, 0, (size_t)NB_BK * 4, stream);

    bhist_kernel<<<(NE + 16383) / 16384, 256, 0, stream>>>(dst, bcnt);
    bscan_kernel<<<1, 1024, 0, stream>>>(bcnt, bbase);
    stage_kernel<<<(NE + 255) / 256, 256, 0, stream>>>(src, dst, bbase, bcur, staging);
    build_kernel<<<NB_BK, 256, 0, stream>>>(staging, bbase, row_ptr, dinv, col);
    gemm1_kernel<<<512, 256, 0, stream>>>(x, W1, dinv, hsb);
    agg1_kernel<<<2048, 256, 0, stream>>>(hsb, row_ptr, col, dinv, b1, h1b);
    gemm2_kernel<<<512, 256, 0, stream>>>(h1b, W2, dinv, hs2b);
    agg2_kernel<<<2048, 256, 0, stream>>>(hs2b, row_ptr, col, dinv, b2, out);
}

// Round 8
// 395.388 us; speedup vs baseline: 1.3072x; 1.3072x over previous
//
#include <hip/hip_runtime.h>
#include <cmath>

#define NN 100000
#define NE 1600000
#define FIN 128
#define HID 128
#define NCLS 40

#define CSH 9                 // coarse bucket = dst >> 9 (512 nodes)
#define CNODES 512
#define NC 196                // ceil(100000/512)
#define CHUNK 8192
#define NCHUNK ((NE + CHUNK - 1) / CHUNK)   // 196

// ---- packed bf16 helpers (RNE) ----
__device__ __forceinline__ unsigned pk_bf16(float a, float b) {
    unsigned ua = __float_as_uint(a);
    unsigned ub = __float_as_uint(b);
    ua += 0x7FFFu + ((ua >> 16) & 1u);
    ub += 0x7FFFu + ((ub >> 16) & 1u);
    return (ua >> 16) | (ub & 0xFFFF0000u);
}
__device__ __forceinline__ float2 upk_bf16(unsigned u) {
    return make_float2(__uint_as_float(u << 16), __uint_as_float(u & 0xFFFF0000u));
}

// ---------------- CSR build v3: chunk-local count-sort, all writes coalesced/block-local ----

// coarse histogram: 196 LDS counters per chunk, flush once
__global__ __launch_bounds__(256) void bhist_kernel(const int* __restrict__ dst,
                                                    int* __restrict__ bcnt) {
    __shared__ int h[NC];
    int tid = threadIdx.x;
    if (tid < NC) h[tid] = 0;
    __syncthreads();
    int base = blockIdx.x * CHUNK;
    int end = min(base + CHUNK, NE);
    for (int e = base + tid; e < end; e += 256) atomicAdd(&h[dst[e] >> CSH], 1);
    __syncthreads();
    if (tid < NC) {
        int v = h[tid];
        if (v) atomicAdd(&bcnt[tid], v);
    }
}

// exclusive scan of bcnt[NC] -> bbase[NC+1]
__global__ __launch_bounds__(256) void bscan_kernel(const int* __restrict__ bcnt,
                                                    int* __restrict__ bbase) {
    __shared__ int t[256];
    int tid = threadIdx.x;
    int v = (tid < NC) ? bcnt[tid] : 0;
    t[tid] = v;
    __syncthreads();
    for (int off = 1; off < 256; off <<= 1) {
        int a = (tid >= off) ? t[tid - off] : 0;
        __syncthreads();
        t[tid] += a;
        __syncthreads();
    }
    if (tid < NC) bbase[tid] = t[tid] - v;
    if (tid == 0) bbase[NC] = NE;
}

// pass A: chunk-local count-sort into bucket-major order, coalesced copy-out
__global__ __launch_bounds__(256) void part_kernel(const int* __restrict__ src,
                                                   const int* __restrict__ dst,
                                                   const int* __restrict__ bbase,
                                                   int* __restrict__ bcur,
                                                   unsigned* __restrict__ staged) {
    __shared__ int cnt[NC], lofs[NC], gofs[NC], lcur[NC];
    __shared__ int tt[256];
    __shared__ unsigned sbuf[CHUNK];         // 32KB
    __shared__ unsigned short bof[CHUNK];    // 16KB
    int tid = threadIdx.x;
    if (tid < NC) { cnt[tid] = 0; lcur[tid] = 0; }
    __syncthreads();
    int base = blockIdx.x * CHUNK;
    int end = min(base + CHUNK, NE);
    for (int e = base + tid; e < end; e += 256) atomicAdd(&cnt[dst[e] >> CSH], 1);
    __syncthreads();
    int v = (tid < NC) ? cnt[tid] : 0;
    tt[tid] = v;
    __syncthreads();
    for (int off = 1; off < 256; off <<= 1) {
        int a = (tid >= off) ? tt[tid - off] : 0;
        __syncthreads();
        tt[tid] += a;
        __syncthreads();
    }
    if (tid < NC) {
        lofs[tid] = tt[tid] - v;
        if (v) gofs[tid] = atomicAdd(&bcur[tid], v);  // reserve bucket space
    }
    __syncthreads();
    for (int e = base + tid; e < end; e += 256) {
        int d = dst[e];
        int b = d >> CSH;
        int p = atomicAdd(&lcur[b], 1);
        int pos = lofs[b] + p;
        sbuf[pos] = ((unsigned)src[e] << CSH) | (unsigned)(d & (CNODES - 1));
        bof[pos] = (unsigned short)b;
    }
    __syncthreads();
    int n = end - base;
    for (int i = tid; i < n; i += 256) {
        int b = bof[i];
        staged[bbase[b] + gofs[b] + (i - lofs[b])] = sbuf[i];
    }
}

// pass B: one block per coarse bucket — row_ptr/dinv/col, writes block-local
__global__ __launch_bounds__(512) void build_kernel(const unsigned* __restrict__ staged,
                                                    const int* __restrict__ bbase,
                                                    int* __restrict__ row_ptr,
                                                    float* __restrict__ dinv,
                                                    int* __restrict__ col) {
    __shared__ int deg[CNODES], cur[CNODES], tt[CNODES];
    int tid = threadIdx.x;
    int b = blockIdx.x;
    int nbase = b << CSH;
    int ebeg = bbase[b], eend = bbase[b + 1];
    int cnt_e = eend - ebeg;
    deg[tid] = 0;
    __syncthreads();
    for (int i = tid; i < cnt_e; i += 512) atomicAdd(&deg[staged[ebeg + i] & (CNODES - 1)], 1);
    __syncthreads();
    int v = deg[tid];
    tt[tid] = v;
    __syncthreads();
    for (int off = 1; off < 512; off <<= 1) {
        int a = (tid >= off) ? tt[tid - off] : 0;
        __syncthreads();
        tt[tid] += a;
        __syncthreads();
    }
    int ex = tt[tid] - v;
    cur[tid] = ex;
    int node = nbase + tid;
    if (node < NN) {
        row_ptr[node] = ebeg + ex;
        dinv[node] = rsqrtf((float)(v + 1));  // +1 self-loop
    }
    if (b == NC - 1 && tid == 0) row_ptr[NN] = NE;
    __syncthreads();
    for (int i = tid; i < cnt_e; i += 512) {
        unsigned u = staged[ebeg + i];
        int p = atomicAdd(&cur[u & (CNODES - 1)], 1);
        col[ebeg + p] = (int)(u >> CSH);
    }
}

// ---------------- GEMM1: hsb = bf16((x @ W1) * dinv[row]) ----------------
__global__ __launch_bounds__(256) void gemm1_kernel(const float* __restrict__ x,
                                                    const float* __restrict__ W1,
                                                    const float* __restrict__ dinv,
                                                    unsigned* __restrict__ hsb) {
    __shared__ float wlds[FIN][HID];   // 64KB, [k][c]
    __shared__ float xlds[32][FIN];    // 16KB, [r][k]
    int tid = threadIdx.x;
    for (int i = tid; i < FIN * HID; i += 256) wlds[i / HID][i % HID] = W1[i];
    int ct = tid & 31;        // c0 = 4*ct
    int rt = tid >> 5;        // r0 = 4*rt (8 tiles -> 32 rows)
    int c0 = ct * 4;
    int nt = (NN + 31) / 32;
    for (int t = blockIdx.x; t < nt; t += gridDim.x) {
        int rowbase = t * 32;
        __syncthreads();
        for (int i = tid; i < 32 * (FIN / 4); i += 256) {
            int r = i / (FIN / 4);
            int k4 = i % (FIN / 4);
            int row = rowbase + r;
            float4 v = (row < NN) ? ((const float4*)x)[(size_t)row * (FIN / 4) + k4]
                                  : make_float4(0.f, 0.f, 0.f, 0.f);
            ((float4*)&xlds[r][0])[k4] = v;
        }
        __syncthreads();
        float acc[4][4];
#pragma unroll
        for (int a = 0; a < 4; ++a)
#pragma unroll
            for (int b = 0; b < 4; ++b) acc[a][b] = 0.f;
        for (int k = 0; k < FIN; k += 4) {
            float4 xv[4], wv[4];
#pragma unroll
            for (int a = 0; a < 4; ++a) xv[a] = *(const float4*)&xlds[rt * 4 + a][k];
#pragma unroll
            for (int kk = 0; kk < 4; ++kk) wv[kk] = *(const float4*)&wlds[k + kk][c0];
#pragma unroll
            for (int kk = 0; kk < 4; ++kk) {
                float4 w = wv[kk];
#pragma unroll
                for (int a = 0; a < 4; ++a) {
                    float xs = ((float*)&xv[a])[kk];
                    acc[a][0] = fmaf(xs, w.x, acc[a][0]);
                    acc[a][1] = fmaf(xs, w.y, acc[a][1]);
                    acc[a][2] = fmaf(xs, w.z, acc[a][2]);
                    acc[a][3] = fmaf(xs, w.w, acc[a][3]);
                }
            }
        }
#pragma unroll
        for (int a = 0; a < 4; ++a) {
            int row = rowbase + rt * 4 + a;
            if (row < NN) {
                float dv = dinv[row];
                uint2 o = make_uint2(pk_bf16(acc[a][0] * dv, acc[a][1] * dv),
                                     pk_bf16(acc[a][2] * dv, acc[a][3] * dv));
                *(uint2*)(hsb + (size_t)row * 64 + ct * 2) = o;
            }
        }
    }
}

// ---------------- agg1: h1b = bf16(relu(dinv[i]*(hs[i] + sum_nbr hs) + b1)) ----------------
__global__ __launch_bounds__(256) void agg1_kernel(const unsigned* __restrict__ hsb,
                                                   const int* __restrict__ row_ptr,
                                                   const int* __restrict__ col,
                                                   const float* __restrict__ dinv,
                                                   const float* __restrict__ b1,
                                                   unsigned* __restrict__ h1b) {
    int wave = (blockIdx.x * blockDim.x + threadIdx.x) >> 6;
    int lane = threadIdx.x & 63;
    int nwaves = (gridDim.x * blockDim.x) >> 6;
    float2 bb = ((const float2*)b1)[lane];
    for (int i = wave; i < NN; i += nwaves) {
        float2 t = upk_bf16(hsb[(size_t)i * 64 + lane]);  // self term
        float ax = t.x, ay = t.y;
        int e = row_ptr[i], s1 = row_ptr[i + 1];
        for (; e + 4 <= s1; e += 4) {
            int sa = col[e + 0], sb = col[e + 1], sc = col[e + 2], sd = col[e + 3];
            unsigned ua = hsb[(size_t)sa * 64 + lane];
            unsigned ub = hsb[(size_t)sb * 64 + lane];
            unsigned uc = hsb[(size_t)sc * 64 + lane];
            unsigned ud = hsb[(size_t)sd * 64 + lane];
            float2 va = upk_bf16(ua), vb = upk_bf16(ub), vc = upk_bf16(uc), vd = upk_bf16(ud);
            ax += va.x + vb.x + vc.x + vd.x;
            ay += va.y + vb.y + vc.y + vd.y;
        }
        for (; e < s1; ++e) {
            float2 v = upk_bf16(hsb[(size_t)col[e] * 64 + lane]);
            ax += v.x;
            ay += v.y;
        }
        float dv = dinv[i];
        float ox = fmaxf(fmaf(ax, dv, bb.x), 0.f);
        float oy = fmaxf(fmaf(ay, dv, bb.y), 0.f);
        h1b[(size_t)i * 64 + lane] = pk_bf16(ox, oy);
    }
}

// ---------------- GEMM2: hs2b = bf16((h1 @ W2) * dinv[row]) ----------------
__global__ __launch_bounds__(256) void gemm2_kernel(const unsigned* __restrict__ h1b,
                                                    const float* __restrict__ W2,
                                                    const float* __restrict__ dinv,
                                                    unsigned* __restrict__ hs2b) {
    __shared__ float wlds[HID][64];   // 32KB zero-padded
    __shared__ float xlds[64][HID];   // 32KB
    int tid = threadIdx.x;
    for (int i = tid; i < HID * 64; i += 256) {
        int k = i / 64, c = i % 64;
        wlds[k][c] = (c < NCLS) ? W2[k * NCLS + c] : 0.f;
    }
    int ct = tid & 15;   // c0 = 4*ct (0..60)
    int rt = tid >> 4;   // 0..15 -> 64 rows
    int c0 = ct * 4;
    int nt = (NN + 63) / 64;
    for (int t = blockIdx.x; t < nt; t += gridDim.x) {
        int rowbase = t * 64;
        __syncthreads();
        // stage h1 (packed bf16) -> f32 LDS
        for (int i = tid; i < 64 * 16; i += 256) {
            int r = i >> 4, q = i & 15;
            int row = rowbase + r;
            uint4 u = (row < NN) ? ((const uint4*)h1b)[(size_t)row * 16 + q]
                                 : make_uint4(0, 0, 0, 0);
            float2 f0 = upk_bf16(u.x), f1 = upk_bf16(u.y);
            float2 f2 = upk_bf16(u.z), f3 = upk_bf16(u.w);
            float* dp = &xlds[r][q * 8];
            ((float4*)dp)[0] = make_float4(f0.x, f0.y, f1.x, f1.y);
            ((float4*)dp)[1] = make_float4(f2.x, f2.y, f3.x, f3.y);
        }
        __syncthreads();
        float acc[4][4];
#pragma unroll
        for (int a = 0; a < 4; ++a)
#pragma unroll
            for (int b = 0; b < 4; ++b) acc[a][b] = 0.f;
        for (int k = 0; k < HID; k += 4) {
            float4 xv[4], wv[4];
#pragma unroll
            for (int a = 0; a < 4; ++a) xv[a] = *(const float4*)&xlds[rt * 4 + a][k];
#pragma unroll
            for (int kk = 0; kk < 4; ++kk) wv[kk] = *(const float4*)&wlds[k + kk][c0];
#pragma unroll
            for (int kk = 0; kk < 4; ++kk) {
                float4 w = wv[kk];
#pragma unroll
                for (int a = 0; a < 4; ++a) {
                    float xs = ((float*)&xv[a])[kk];
                    acc[a][0] = fmaf(xs, w.x, acc[a][0]);
                    acc[a][1] = fmaf(xs, w.y, acc[a][1]);
                    acc[a][2] = fmaf(xs, w.z, acc[a][2]);
                    acc[a][3] = fmaf(xs, w.w, acc[a][3]);
                }
            }
        }
        if (c0 < NCLS) {
#pragma unroll
            for (int a = 0; a < 4; ++a) {
                int row = rowbase + rt * 4 + a;
                if (row < NN) {
                    float dv = dinv[row];
                    uint2 o = make_uint2(pk_bf16(acc[a][0] * dv, acc[a][1] * dv),
                                         pk_bf16(acc[a][2] * dv, acc[a][3] * dv));
                    *(uint2*)(hs2b + (size_t)row * 20 + ct * 2) = o;
                }
            }
        }
    }
}

// ---------------- agg2 + bias + log_softmax ----------------
__global__ __launch_bounds__(256) void agg2_kernel(const unsigned* __restrict__ hs2b,
                                                   const int* __restrict__ row_ptr,
                                                   const int* __restrict__ col,
                                                   const float* __restrict__ dinv,
                                                   const float* __restrict__ b2,
                                                   float* __restrict__ out) {
    int wave = (blockIdx.x * blockDim.x + threadIdx.x) >> 6;
    int lane = threadIdx.x & 63;
    int nwaves = (gridDim.x * blockDim.x) >> 6;
    bool act = lane < (NCLS / 2);
    float2 bb = act ? ((const float2*)b2)[lane] : make_float2(0.f, 0.f);
    for (int i = wave; i < NN; i += nwaves) {
        float ax = 0.f, ay = 0.f;
        if (act) {
            float2 t = upk_bf16(hs2b[(size_t)i * 20 + lane]);  // self term
            ax = t.x; ay = t.y;
        }
        int e = row_ptr[i], s1 = row_ptr[i + 1];
        for (; e + 4 <= s1; e += 4) {
            int sa = col[e + 0], sb = col[e + 1], sc = col[e + 2], sd = col[e + 3];
            if (act) {
                float2 va = upk_bf16(hs2b[(size_t)sa * 20 + lane]);
                float2 vb = upk_bf16(hs2b[(size_t)sb * 20 + lane]);
                float2 vc = upk_bf16(hs2b[(size_t)sc * 20 + lane]);
                float2 vd = upk_bf16(hs2b[(size_t)sd * 20 + lane]);
                ax += va.x + vb.x + vc.x + vd.x;
                ay += va.y + vb.y + vc.y + vd.y;
            }
        }
        for (; e < s1; ++e) {
            int s = col[e];
            if (act) {
                float2 v = upk_bf16(hs2b[(size_t)s * 20 + lane]);
                ax += v.x;
                ay += v.y;
            }
        }
        float dv = dinv[i];
        float lx = fmaf(ax, dv, bb.x);
        float ly = fmaf(ay, dv, bb.y);
        float m = act ? fmaxf(lx, ly) : -INFINITY;
#pragma unroll
        for (int off = 32; off; off >>= 1) m = fmaxf(m, __shfl_xor(m, off));
        float ssum = act ? (expf(lx - m) + expf(ly - m)) : 0.f;
#pragma unroll
        for (int off = 32; off; off >>= 1) ssum += __shfl_xor(ssum, off);
        float ls = logf(ssum);
        if (act) {
            float2 o = make_float2(lx - m - ls, ly - m - ls);
            ((float2*)(out + (size_t)i * NCLS))[lane] = o;
        }
    }
}

extern "C" void kernel_launch(void* const* d_in, const int* in_sizes, int n_in,
                              void* d_out, int out_size, void* d_ws, size_t ws_size,
                              hipStream_t stream) {
    const float* x = (const float*)d_in[0];
    const int* edge_index = (const int*)d_in[1];
    const float* W1 = (const float*)d_in[2];
    const float* b1 = (const float*)d_in[3];
    const float* W2 = (const float*)d_in[4];
    const float* b2 = (const float*)d_in[5];
    float* out = (float*)d_out;
    const int* src = edge_index;          // edge_index[0]
    const int* dst = edge_index + NE;     // edge_index[1]

    char* ws = (char*)d_ws;
    size_t off = 0;
    auto alloc = [&](size_t bytes) -> void* {
        void* p = (void*)(ws + off);
        off += (bytes + 255) & ~(size_t)255;
        return p;
    };
    int* bcnt = (int*)alloc((size_t)NC * 4);
    int* bbase = (int*)alloc((size_t)(NC + 1) * 4);
    int* bcur = (int*)alloc((size_t)NC * 4);
    int* row_ptr = (int*)alloc((size_t)(NN + 1) * 4);
    int* col = (int*)alloc((size_t)NE * 4);
    float* dinv = (float*)alloc((size_t)NN * 4);
    unsigned* hsb = (unsigned*)alloc((size_t)NN * 64 * 4);   // bf16x2 packed [NN][64]
    unsigned* h1b = (unsigned*)alloc((size_t)NN * 64 * 4);   // bf16x2 packed [NN][64]
    unsigned* hs2b = (unsigned*)alloc((size_t)NN * 20 * 4);  // bf16x2 packed [NN][20]
    unsigned* staged = h1b;  // alias: staged fully consumed by build before agg1 writes h1b

    hipMemsetAsync(bcnt, 0, (size_t)NC * 4, stream);
    hipMemsetAsync(bcur, 0, (size_t)NC * 4, stream);

    bhist_kernel<<<NCHUNK, 256, 0, stream>>>(dst, bcnt);
    bscan_kernel<<<1, 256, 0, stream>>>(bcnt, bbase);
    part_kernel<<<NCHUNK, 256, 0, stream>>>(src, dst, bbase, bcur, staged);
    build_kernel<<<NC, 512, 0, stream>>>(staged, bbase, row_ptr, dinv, col);
    gemm1_kernel<<<512, 256, 0, stream>>>(x, W1, dinv, hsb);
    agg1_kernel<<<2048, 256, 0, stream>>>(hsb, row_ptr, col, dinv, b1, h1b);
    gemm2_kernel<<<512, 256, 0, stream>>>(h1b, W2, dinv, hs2b);
    agg2_kernel<<<2048, 256, 0, stream>>>(hs2b, row_ptr, col, dinv, b2, out);
}

// Round 12
// 366.030 us; speedup vs baseline: 1.4121x; 1.0802x over previous
//
#include <hip/hip_runtime.h>
#include <cmath>

#define NN 100000
#define NE 1600000
#define FIN 128
#define HID 128
#define NCLS 40

#define CSH 9                 // coarse bucket = dst >> 9 (512 nodes)
#define CNODES 512
#define NC 196                // ceil(100000/512)
#define CHUNK 8192
#define NCHUNK ((NE + CHUNK - 1) / CHUNK)   // 196

#define KP 136                // padded LDS row length (bf16) -> 272 B, 16B-aligned, 2-way banks

typedef __attribute__((ext_vector_type(8))) short bf16x8;
typedef __attribute__((ext_vector_type(4))) float f32x4;

// ---- packed bf16 helpers (RNE) ----
__device__ __forceinline__ unsigned pk_bf16(float a, float b) {
    unsigned ua = __float_as_uint(a);
    unsigned ub = __float_as_uint(b);
    ua += 0x7FFFu + ((ua >> 16) & 1u);
    ub += 0x7FFFu + ((ub >> 16) & 1u);
    return (ua >> 16) | (ub & 0xFFFF0000u);
}
__device__ __forceinline__ float2 upk_bf16(unsigned u) {
    return make_float2(__uint_as_float(u << 16), __uint_as_float(u & 0xFFFF0000u));
}
__device__ __forceinline__ unsigned short bf16r(float f) {
    unsigned u = __float_as_uint(f);
    u += 0x7FFFu + ((u >> 16) & 1u);
    return (unsigned short)(u >> 16);
}

// ---------------- CSR build v3 (unchanged from R8) ----------------

__global__ __launch_bounds__(256) void bhist_kernel(const int* __restrict__ dst,
                                                    int* __restrict__ bcnt) {
    __shared__ int h[NC];
    int tid = threadIdx.x;
    if (tid < NC) h[tid] = 0;
    __syncthreads();
    int base = blockIdx.x * CHUNK;
    int end = min(base + CHUNK, NE);
    for (int e = base + tid; e < end; e += 256) atomicAdd(&h[dst[e] >> CSH], 1);
    __syncthreads();
    if (tid < NC) {
        int v = h[tid];
        if (v) atomicAdd(&bcnt[tid], v);
    }
}

__global__ __launch_bounds__(256) void bscan_kernel(const int* __restrict__ bcnt,
                                                    int* __restrict__ bbase) {
    __shared__ int t[256];
    int tid = threadIdx.x;
    int v = (tid < NC) ? bcnt[tid] : 0;
    t[tid] = v;
    __syncthreads();
    for (int off = 1; off < 256; off <<= 1) {
        int a = (tid >= off) ? t[tid - off] : 0;
        __syncthreads();
        t[tid] += a;
        __syncthreads();
    }
    if (tid < NC) bbase[tid] = t[tid] - v;
    if (tid == 0) bbase[NC] = NE;
}

__global__ __launch_bounds__(256) void part_kernel(const int* __restrict__ src,
                                                   const int* __restrict__ dst,
                                                   const int* __restrict__ bbase,
                                                   int* __restrict__ bcur,
                                                   unsigned* __restrict__ staged) {
    __shared__ int cnt[NC], lofs[NC], gofs[NC], lcur[NC];
    __shared__ int tt[256];
    __shared__ unsigned sbuf[CHUNK];         // 32KB
    __shared__ unsigned short bof[CHUNK];    // 16KB
    int tid = threadIdx.x;
    if (tid < NC) { cnt[tid] = 0; lcur[tid] = 0; }
    __syncthreads();
    int base = blockIdx.x * CHUNK;
    int end = min(base + CHUNK, NE);
    for (int e = base + tid; e < end; e += 256) atomicAdd(&cnt[dst[e] >> CSH], 1);
    __syncthreads();
    int v = (tid < NC) ? cnt[tid] : 0;
    tt[tid] = v;
    __syncthreads();
    for (int off = 1; off < 256; off <<= 1) {
        int a = (tid >= off) ? tt[tid - off] : 0;
        __syncthreads();
        tt[tid] += a;
        __syncthreads();
    }
    if (tid < NC) {
        lofs[tid] = tt[tid] - v;
        if (v) gofs[tid] = atomicAdd(&bcur[tid], v);
    }
    __syncthreads();
    for (int e = base + tid; e < end; e += 256) {
        int d = dst[e];
        int b = d >> CSH;
        int p = atomicAdd(&lcur[b], 1);
        int pos = lofs[b] + p;
        sbuf[pos] = ((unsigned)src[e] << CSH) | (unsigned)(d & (CNODES - 1));
        bof[pos] = (unsigned short)b;
    }
    __syncthreads();
    int n = end - base;
    for (int i = tid; i < n; i += 256) {
        int b = bof[i];
        staged[bbase[b] + gofs[b] + (i - lofs[b])] = sbuf[i];
    }
}

__global__ __launch_bounds__(512) void build_kernel(const unsigned* __restrict__ staged,
                                                    const int* __restrict__ bbase,
                                                    int* __restrict__ row_ptr,
                                                    float* __restrict__ dinv,
                                                    int* __restrict__ col) {
    __shared__ int deg[CNODES], cur[CNODES], tt[CNODES];
    int tid = threadIdx.x;
    int b = blockIdx.x;
    int nbase = b << CSH;
    int ebeg = bbase[b], eend = bbase[b + 1];
    int cnt_e = eend - ebeg;
    deg[tid] = 0;
    __syncthreads();
    for (int i = tid; i < cnt_e; i += 512) atomicAdd(&deg[staged[ebeg + i] & (CNODES - 1)], 1);
    __syncthreads();
    int v = deg[tid];
    tt[tid] = v;
    __syncthreads();
    for (int off = 1; off < 512; off <<= 1) {
        int a = (tid >= off) ? tt[tid - off] : 0;
        __syncthreads();
        tt[tid] += a;
        __syncthreads();
    }
    int ex = tt[tid] - v;
    cur[tid] = ex;
    int node = nbase + tid;
    if (node < NN) {
        row_ptr[node] = ebeg + ex;
        dinv[node] = rsqrtf((float)(v + 1));  // +1 self-loop
    }
    if (b == NC - 1 && tid == 0) row_ptr[NN] = NE;
    __syncthreads();
    for (int i = tid; i < cnt_e; i += 512) {
        unsigned u = staged[ebeg + i];
        int p = atomicAdd(&cur[u & (CNODES - 1)], 1);
        col[ebeg + p] = (int)(u >> CSH);
    }
}

// ---------------- GEMM1 (MFMA bf16): hsb = bf16((x @ W1) * dinv[row]) ----------------
// 64 rows x 128 cols per block, 4 waves (16 rows each), K=128 in 4 MFMA steps.
// Output slot permutation: dword slot s = t*16+c holds features (32t+c, 32t+c+16).
__global__ __launch_bounds__(256) void gemm1_kernel(const float* __restrict__ x,
                                                    const float* __restrict__ W1,
                                                    const float* __restrict__ dinv,
                                                    unsigned* __restrict__ hsb) {
    __shared__ unsigned short wt[HID][KP];   // W1^T bf16 [n][k]
    __shared__ unsigned short xt[64][KP];    // x tile bf16 [r][k]
    __shared__ float dv[64];
    int tid = threadIdx.x;
    int lane = tid & 63;
    int w = tid >> 6;
    // stage W1^T (once per block): i -> k = i>>5, n4 = i&31
    for (int i = tid; i < FIN * 32; i += 256) {
        int k = i >> 5, n4 = i & 31;
        float4 v = ((const float4*)W1)[k * 32 + n4];
        wt[n4 * 4 + 0][k] = bf16r(v.x);
        wt[n4 * 4 + 1][k] = bf16r(v.y);
        wt[n4 * 4 + 2][k] = bf16r(v.z);
        wt[n4 * 4 + 3][k] = bf16r(v.w);
    }
    int nt = (NN + 63) / 64;
    for (int t = blockIdx.x; t < nt; t += gridDim.x) {
        int rowbase = t * 64;
        __syncthreads();  // wt ready (iter 1); xt consumed (iter >1)
        for (int i = tid; i < 64 * 32; i += 256) {
            int r = i >> 5, seg = i & 31;
            int row = rowbase + r;
            float4 v = (row < NN) ? ((const float4*)x)[(size_t)row * 32 + seg]
                                  : make_float4(0.f, 0.f, 0.f, 0.f);
            xt[r][seg * 4 + 0] = bf16r(v.x);
            xt[r][seg * 4 + 1] = bf16r(v.y);
            xt[r][seg * 4 + 2] = bf16r(v.z);
            xt[r][seg * 4 + 3] = bf16r(v.w);
        }
        if (tid < 64) {
            int row = rowbase + tid;
            dv[tid] = (row < NN) ? dinv[row] : 1.0f;
        }
        __syncthreads();
        f32x4 acc[8];
#pragma unroll
        for (int c = 0; c < 8; ++c) acc[c] = (f32x4){0.f, 0.f, 0.f, 0.f};
        int arow = w * 16 + (lane & 15);
        int koff = (lane >> 4) * 8;
#pragma unroll
        for (int k0 = 0; k0 < FIN; k0 += 32) {
            bf16x8 av = *(const bf16x8*)&xt[arow][k0 + koff];
#pragma unroll
            for (int ct = 0; ct < 8; ++ct) {
                bf16x8 bv = *(const bf16x8*)&wt[ct * 16 + (lane & 15)][k0 + koff];
                acc[ct] = __builtin_amdgcn_mfma_f32_16x16x32_bf16(av, bv, acc[ct], 0, 0, 0);
            }
        }
        int rl0 = w * 16 + (lane >> 4) * 4;
#pragma unroll
        for (int r = 0; r < 4; ++r) {
            int row = rowbase + rl0 + r;
            if (row < NN) {
                float dvr = dv[rl0 + r];
#pragma unroll
                for (int tp = 0; tp < 4; ++tp) {
                    unsigned val = pk_bf16(acc[2 * tp][r] * dvr, acc[2 * tp + 1][r] * dvr);
                    hsb[(size_t)row * 64 + tp * 16 + (lane & 15)] = val;
                }
            }
        }
    }
}

// ---------------- agg1: slot-elementwise; slot s holds features (32*(s>>4)+(s&15), +16) ----
__global__ __launch_bounds__(256) void agg1_kernel(const unsigned* __restrict__ hsb,
                                                   const int* __restrict__ row_ptr,
                                                   const int* __restrict__ col,
                                                   const float* __restrict__ dinv,
                                                   const float* __restrict__ b1,
                                                   unsigned* __restrict__ h1b) {
    int wave = (blockIdx.x * blockDim.x + threadIdx.x) >> 6;
    int lane = threadIdx.x & 63;
    int nwaves = (gridDim.x * blockDim.x) >> 6;
    int f0 = 32 * (lane >> 4) + (lane & 15);
    float bx = b1[f0];
    float by = b1[f0 + 16];
    for (int i = wave; i < NN; i += nwaves) {
        float2 t = upk_bf16(hsb[(size_t)i * 64 + lane]);  // self term
        float ax = t.x, ay = t.y;
        int e = row_ptr[i], s1 = row_ptr[i + 1];
        for (; e + 4 <= s1; e += 4) {
            int sa = col[e + 0], sb = col[e + 1], sc = col[e + 2], sd = col[e + 3];
            unsigned ua = hsb[(size_t)sa * 64 + lane];
            unsigned ub = hsb[(size_t)sb * 64 + lane];
            unsigned uc = hsb[(size_t)sc * 64 + lane];
            unsigned ud = hsb[(size_t)sd * 64 + lane];
            float2 va = upk_bf16(ua), vb = upk_bf16(ub), vc = upk_bf16(uc), vd = upk_bf16(ud);
            ax += va.x + vb.x + vc.x + vd.x;
            ay += va.y + vb.y + vc.y + vd.y;
        }
        for (; e < s1; ++e) {
            float2 v = upk_bf16(hsb[(size_t)col[e] * 64 + lane]);
            ax += v.x;
            ay += v.y;
        }
        float dvv = dinv[i];
        float ox = fmaxf(fmaf(ax, dvv, bx), 0.f);
        float oy = fmaxf(fmaf(ay, dvv, by), 0.f);
        h1b[(size_t)i * 64 + lane] = pk_bf16(ox, oy);
    }
}

// ---------------- GEMM2: hs2b = bf16((h1 @ W2) * dinv[row]) ----------------
// h1b slots are permuted; compensate via W2 row remap during LDS staging.
__global__ __launch_bounds__(256) void gemm2_kernel(const unsigned* __restrict__ h1b,
                                                    const float* __restrict__ W2,
                                                    const float* __restrict__ dinv,
                                                    unsigned* __restrict__ hs2b) {
    __shared__ float wlds[HID][64];   // 32KB zero-padded, k-index in PERMUTED slot order
    __shared__ float xlds[64][HID];   // 32KB
    int tid = threadIdx.x;
    for (int i = tid; i < HID * 64; i += 256) {
        int kk = i / 64, c = i % 64;
        int s = kk >> 1, half = kk & 1;
        int realk = 32 * (s >> 4) + 16 * half + (s & 15);
        wlds[kk][c] = (c < NCLS) ? W2[realk * NCLS + c] : 0.f;
    }
    int ct = tid & 15;   // c0 = 4*ct (0..60)
    int rt = tid >> 4;   // 0..15 -> 64 rows
    int c0 = ct * 4;
    int nt = (NN + 63) / 64;
    for (int t = blockIdx.x; t < nt; t += gridDim.x) {
        int rowbase = t * 64;
        __syncthreads();
        for (int i = tid; i < 64 * 16; i += 256) {
            int r = i >> 4, q = i & 15;
            int row = rowbase + r;
            uint4 u = (row < NN) ? ((const uint4*)h1b)[(size_t)row * 16 + q]
                                 : make_uint4(0, 0, 0, 0);
            float2 g0 = upk_bf16(u.x), g1 = upk_bf16(u.y);
            float2 g2 = upk_bf16(u.z), g3 = upk_bf16(u.w);
            float* dp = &xlds[r][q * 8];
            ((float4*)dp)[0] = make_float4(g0.x, g0.y, g1.x, g1.y);
            ((float4*)dp)[1] = make_float4(g2.x, g2.y, g3.x, g3.y);
        }
        __syncthreads();
        float acc[4][4];
#pragma unroll
        for (int a = 0; a < 4; ++a)
#pragma unroll
            for (int b = 0; b < 4; ++b) acc[a][b] = 0.f;
        for (int k = 0; k < HID; k += 4) {
            float4 xv[4], wv[4];
#pragma unroll
            for (int a = 0; a < 4; ++a) xv[a] = *(const float4*)&xlds[rt * 4 + a][k];
#pragma unroll
            for (int kk = 0; kk < 4; ++kk) wv[kk] = *(const float4*)&wlds[k + kk][c0];
#pragma unroll
            for (int kk = 0; kk < 4; ++kk) {
                float4 w = wv[kk];
#pragma unroll
                for (int a = 0; a < 4; ++a) {
                    float xs = ((float*)&xv[a])[kk];
                    acc[a][0] = fmaf(xs, w.x, acc[a][0]);
                    acc[a][1] = fmaf(xs, w.y, acc[a][1]);
                    acc[a][2] = fmaf(xs, w.z, acc[a][2]);
                    acc[a][3] = fmaf(xs, w.w, acc[a][3]);
                }
            }
        }
        if (c0 < NCLS) {
#pragma unroll
            for (int a = 0; a < 4; ++a) {
                int row = rowbase + rt * 4 + a;
                if (row < NN) {
                    float dvv = dinv[row];
                    uint2 o = make_uint2(pk_bf16(acc[a][0] * dvv, acc[a][1] * dvv),
                                         pk_bf16(acc[a][2] * dvv, acc[a][3] * dvv));
                    *(uint2*)(hs2b + (size_t)row * 20 + ct * 2) = o;
                }
            }
        }
    }
}

// ---------------- agg2 + bias + log_softmax (unchanged) ----------------
__global__ __launch_bounds__(256) void agg2_kernel(const unsigned* __restrict__ hs2b,
                                                   const int* __restrict__ row_ptr,
                                                   const int* __restrict__ col,
                                                   const float* __restrict__ dinv,
                                                   const float* __restrict__ b2,
                                                   float* __restrict__ out) {
    int wave = (blockIdx.x * blockDim.x + threadIdx.x) >> 6;
    int lane = threadIdx.x & 63;
    int nwaves = (gridDim.x * blockDim.x) >> 6;
    bool act = lane < (NCLS / 2);
    float2 bb = act ? ((const float2*)b2)[lane] : make_float2(0.f, 0.f);
    for (int i = wave; i < NN; i += nwaves) {
        float ax = 0.f, ay = 0.f;
        if (act) {
            float2 t = upk_bf16(hs2b[(size_t)i * 20 + lane]);  // self term
            ax = t.x; ay = t.y;
        }
        int e = row_ptr[i], s1 = row_ptr[i + 1];
        for (; e + 4 <= s1; e += 4) {
            int sa = col[e + 0], sb = col[e + 1], sc = col[e + 2], sd = col[e + 3];
            if (act) {
                float2 va = upk_bf16(hs2b[(size_t)sa * 20 + lane]);
                float2 vb = upk_bf16(hs2b[(size_t)sb * 20 + lane]);
                float2 vc = upk_bf16(hs2b[(size_t)sc * 20 + lane]);
                float2 vd = upk_bf16(hs2b[(size_t)sd * 20 + lane]);
                ax += va.x + vb.x + vc.x + vd.x;
                ay += va.y + vb.y + vc.y + vd.y;
            }
        }
        for (; e < s1; ++e) {
            int s = col[e];
            if (act) {
                float2 v = upk_bf16(hs2b[(size_t)s * 20 + lane]);
                ax += v.x;
                ay += v.y;
            }
        }
        float dvv = dinv[i];
        float lx = fmaf(ax, dvv, bb.x);
        float ly = fmaf(ay, dvv, bb.y);
        float m = act ? fmaxf(lx, ly) : -INFINITY;
#pragma unroll
        for (int off = 32; off; off >>= 1) m = fmaxf(m, __shfl_xor(m, off));
        float ssum = act ? (expf(lx - m) + expf(ly - m)) : 0.f;
#pragma unroll
        for (int off = 32; off; off >>= 1) ssum += __shfl_xor(ssum, off);
        float ls = logf(ssum);
        if (act) {
            float2 o = make_float2(lx - m - ls, ly - m - ls);
            ((float2*)(out + (size_t)i * NCLS))[lane] = o;
        }
    }
}

extern "C" void kernel_launch(void* const* d_in, const int* in_sizes, int n_in,
                              void* d_out, int out_size, void* d_ws, size_t ws_size,
                              hipStream_t stream) {
    const float* x = (const float*)d_in[0];
    const int* edge_index = (const int*)d_in[1];
    const float* W1 = (const float*)d_in[2];
    const float* b1 = (const float*)d_in[3];
    const float* W2 = (const float*)d_in[4];
    const float* b2 = (const float*)d_in[5];
    float* out = (float*)d_out;
    const int* src = edge_index;          // edge_index[0]
    const int* dst = edge_index + NE;     // edge_index[1]

    char* ws = (char*)d_ws;
    size_t off = 0;
    auto alloc = [&](size_t bytes) -> void* {
        void* p = (void*)(ws + off);
        off += (bytes + 255) & ~(size_t)255;
        return p;
    };
    int* bcnt = (int*)alloc((size_t)NC * 4);
    int* bbase = (int*)alloc((size_t)(NC + 1) * 4);
    int* bcur = (int*)alloc((size_t)NC * 4);
    int* row_ptr = (int*)alloc((size_t)(NN + 1) * 4);
    int* col = (int*)alloc((size_t)NE * 4);
    float* dinv = (float*)alloc((size_t)NN * 4);
    unsigned* hsb = (unsigned*)alloc((size_t)NN * 64 * 4);   // bf16x2 packed [NN][64] (slot-permuted)
    unsigned* h1b = (unsigned*)alloc((size_t)NN * 64 * 4);   // bf16x2 packed [NN][64] (slot-permuted)
    unsigned* hs2b = (unsigned*)alloc((size_t)NN * 20 * 4);  // bf16x2 packed [NN][20]
    unsigned* staged = h1b;  // alias: staged fully consumed by build before agg1 writes h1b

    hipMemsetAsync(bcnt, 0, (size_t)NC * 4, stream);
    hipMemsetAsync(bcur, 0, (size_t)NC * 4, stream);

    bhist_kernel<<<NCHUNK, 256, 0, stream>>>(dst, bcnt);
    bscan_kernel<<<1, 256, 0, stream>>>(bcnt, bbase);
    part_kernel<<<NCHUNK, 256, 0, stream>>>(src, dst, bbase, bcur, staged);
    build_kernel<<<NC, 512, 0, stream>>>(staged, bbase, row_ptr, dinv, col);
    gemm1_kernel<<<768, 256, 0, stream>>>(x, W1, dinv, hsb);
    agg1_kernel<<<2048, 256, 0, stream>>>(hsb, row_ptr, col, dinv, b1, h1b);
    gemm2_kernel<<<512, 256, 0, stream>>>(h1b, W2, dinv, hs2b);
    agg2_kernel<<<2048, 256, 0, stream>>>(hs2b, row_ptr, col, dinv, b2, out);
}

// Round 15
// 341.265 us; speedup vs baseline: 1.5145x; 1.0726x over previous
//
#include <hip/hip_runtime.h>
#include <cmath>

#define NN 100000
#define NE 1600000
#define FIN 128
#define HID 128
#define NCLS 40

#define CSH 9                 // coarse bucket = dst >> 9 (512 nodes)
#define CNODES 512
#define NC 196                // ceil(100000/512)
#define CHUNK 8192
#define NCHUNK ((NE + CHUNK - 1) / CHUNK)   // 196

#define KP 136                // padded LDS row length (bf16) -> 272 B, 16B-aligned, 2-way banks

typedef __attribute__((ext_vector_type(8))) short bf16x8;
typedef __attribute__((ext_vector_type(4))) float f32x4;

// ---- packed bf16 helpers (RNE) ----
__device__ __forceinline__ unsigned pk_bf16(float a, float b) {
    unsigned ua = __float_as_uint(a);
    unsigned ub = __float_as_uint(b);
    ua += 0x7FFFu + ((ua >> 16) & 1u);
    ub += 0x7FFFu + ((ub >> 16) & 1u);
    return (ua >> 16) | (ub & 0xFFFF0000u);
}
__device__ __forceinline__ float2 upk_bf16(unsigned u) {
    return make_float2(__uint_as_float(u << 16), __uint_as_float(u & 0xFFFF0000u));
}
__device__ __forceinline__ unsigned short bf16r(float f) {
    unsigned u = __float_as_uint(f);
    u += 0x7FFFu + ((u >> 16) & 1u);
    return (unsigned short)(u >> 16);
}

// ---------------- CSR build v3 (unchanged from R8) ----------------

__global__ __launch_bounds__(256) void bhist_kernel(const int* __restrict__ dst,
                                                    int* __restrict__ bcnt) {
    __shared__ int h[NC];
    int tid = threadIdx.x;
    if (tid < NC) h[tid] = 0;
    __syncthreads();
    int base = blockIdx.x * CHUNK;
    int end = min(base + CHUNK, NE);
    for (int e = base + tid; e < end; e += 256) atomicAdd(&h[dst[e] >> CSH], 1);
    __syncthreads();
    if (tid < NC) {
        int v = h[tid];
        if (v) atomicAdd(&bcnt[tid], v);
    }
}

__global__ __launch_bounds__(256) void bscan_kernel(const int* __restrict__ bcnt,
                                                    int* __restrict__ bbase) {
    __shared__ int t[256];
    int tid = threadIdx.x;
    int v = (tid < NC) ? bcnt[tid] : 0;
    t[tid] = v;
    __syncthreads();
    for (int off = 1; off < 256; off <<= 1) {
        int a = (tid >= off) ? t[tid - off] : 0;
        __syncthreads();
        t[tid] += a;
        __syncthreads();
    }
    if (tid < NC) bbase[tid] = t[tid] - v;
    if (tid == 0) bbase[NC] = NE;
}

__global__ __launch_bounds__(256) void part_kernel(const int* __restrict__ src,
                                                   const int* __restrict__ dst,
                                                   const int* __restrict__ bbase,
                                                   int* __restrict__ bcur,
                                                   unsigned* __restrict__ staged) {
    __shared__ int cnt[NC], lofs[NC], gofs[NC], lcur[NC];
    __shared__ int tt[256];
    __shared__ unsigned sbuf[CHUNK];         // 32KB
    __shared__ unsigned short bof[CHUNK];    // 16KB
    int tid = threadIdx.x;
    if (tid < NC) { cnt[tid] = 0; lcur[tid] = 0; }
    __syncthreads();
    int base = blockIdx.x * CHUNK;
    int end = min(base + CHUNK, NE);
    for (int e = base + tid; e < end; e += 256) atomicAdd(&cnt[dst[e] >> CSH], 1);
    __syncthreads();
    int v = (tid < NC) ? cnt[tid] : 0;
    tt[tid] = v;
    __syncthreads();
    for (int off = 1; off < 256; off <<= 1) {
        int a = (tid >= off) ? tt[tid - off] : 0;
        __syncthreads();
        tt[tid] += a;
        __syncthreads();
    }
    if (tid < NC) {
        lofs[tid] = tt[tid] - v;
        if (v) gofs[tid] = atomicAdd(&bcur[tid], v);
    }
    __syncthreads();
    for (int e = base + tid; e < end; e += 256) {
        int d = dst[e];
        int b = d >> CSH;
        int p = atomicAdd(&lcur[b], 1);
        int pos = lofs[b] + p;
        sbuf[pos] = ((unsigned)src[e] << CSH) | (unsigned)(d & (CNODES - 1));
        bof[pos] = (unsigned short)b;
    }
    __syncthreads();
    int n = end - base;
    for (int i = tid; i < n; i += 256) {
        int b = bof[i];
        staged[bbase[b] + gofs[b] + (i - lofs[b])] = sbuf[i];
    }
}

__global__ __launch_bounds__(512) void build_kernel(const unsigned* __restrict__ staged,
                                                    const int* __restrict__ bbase,
                                                    int* __restrict__ row_ptr,
                                                    float* __restrict__ dinv,
                                                    int* __restrict__ col) {
    __shared__ int deg[CNODES], cur[CNODES], tt[CNODES];
    int tid = threadIdx.x;
    int b = blockIdx.x;
    int nbase = b << CSH;
    int ebeg = bbase[b], eend = bbase[b + 1];
    int cnt_e = eend - ebeg;
    deg[tid] = 0;
    __syncthreads();
    for (int i = tid; i < cnt_e; i += 512) atomicAdd(&deg[staged[ebeg + i] & (CNODES - 1)], 1);
    __syncthreads();
    int v = deg[tid];
    tt[tid] = v;
    __syncthreads();
    for (int off = 1; off < 512; off <<= 1) {
        int a = (tid >= off) ? tt[tid - off] : 0;
        __syncthreads();
        tt[tid] += a;
        __syncthreads();
    }
    int ex = tt[tid] - v;
    cur[tid] = ex;
    int node = nbase + tid;
    if (node < NN) {
        row_ptr[node] = ebeg + ex;
        dinv[node] = rsqrtf((float)(v + 1));  // +1 self-loop
    }
    if (b == NC - 1 && tid == 0) row_ptr[NN] = NE;
    __syncthreads();
    for (int i = tid; i < cnt_e; i += 512) {
        unsigned u = staged[ebeg + i];
        int p = atomicAdd(&cur[u & (CNODES - 1)], 1);
        col[ebeg + p] = (int)(u >> CSH);
    }
}

// ---------------- GEMM1 (MFMA bf16): hsb = bf16((x @ W1) * dinv[row]) ----------------
// 64 rows x 128 cols per block, 4 waves (16 rows each), K=128 in 4 MFMA steps.
// Output slot permutation: dword slot s = t*16+c holds features (32t+c, 32t+c+16).
__global__ __launch_bounds__(256) void gemm1_kernel(const float* __restrict__ x,
                                                    const float* __restrict__ W1,
                                                    const float* __restrict__ dinv,
                                                    unsigned* __restrict__ hsb) {
    __shared__ unsigned short wt[HID][KP];   // W1^T bf16 [n][k]
    __shared__ unsigned short xt[64][KP];    // x tile bf16 [r][k]
    __shared__ float dv[64];
    int tid = threadIdx.x;
    int lane = tid & 63;
    int w = tid >> 6;
    // stage W1^T (once per block): i -> k = i>>5, n4 = i&31
    for (int i = tid; i < FIN * 32; i += 256) {
        int k = i >> 5, n4 = i & 31;
        float4 v = ((const float4*)W1)[k * 32 + n4];
        wt[n4 * 4 + 0][k] = bf16r(v.x);
        wt[n4 * 4 + 1][k] = bf16r(v.y);
        wt[n4 * 4 + 2][k] = bf16r(v.z);
        wt[n4 * 4 + 3][k] = bf16r(v.w);
    }
    int nt = (NN + 63) / 64;
    for (int t = blockIdx.x; t < nt; t += gridDim.x) {
        int rowbase = t * 64;
        __syncthreads();  // wt ready (iter 1); xt consumed (iter >1)
        for (int i = tid; i < 64 * 32; i += 256) {
            int r = i >> 5, seg = i & 31;
            int row = rowbase + r;
            float4 v = (row < NN) ? ((const float4*)x)[(size_t)row * 32 + seg]
                                  : make_float4(0.f, 0.f, 0.f, 0.f);
            xt[r][seg * 4 + 0] = bf16r(v.x);
            xt[r][seg * 4 + 1] = bf16r(v.y);
            xt[r][seg * 4 + 2] = bf16r(v.z);
            xt[r][seg * 4 + 3] = bf16r(v.w);
        }
        if (tid < 64) {
            int row = rowbase + tid;
            dv[tid] = (row < NN) ? dinv[row] : 1.0f;
        }
        __syncthreads();
        f32x4 acc[8];
#pragma unroll
        for (int c = 0; c < 8; ++c) acc[c] = (f32x4){0.f, 0.f, 0.f, 0.f};
        int arow = w * 16 + (lane & 15);
        int koff = (lane >> 4) * 8;
#pragma unroll
        for (int k0 = 0; k0 < FIN; k0 += 32) {
            bf16x8 av = *(const bf16x8*)&xt[arow][k0 + koff];
#pragma unroll
            for (int ct = 0; ct < 8; ++ct) {
                bf16x8 bv = *(const bf16x8*)&wt[ct * 16 + (lane & 15)][k0 + koff];
                acc[ct] = __builtin_amdgcn_mfma_f32_16x16x32_bf16(av, bv, acc[ct], 0, 0, 0);
            }
        }
        int rl0 = w * 16 + (lane >> 4) * 4;
#pragma unroll
        for (int r = 0; r < 4; ++r) {
            int row = rowbase + rl0 + r;
            if (row < NN) {
                float dvr = dv[rl0 + r];
#pragma unroll
                for (int tp = 0; tp < 4; ++tp) {
                    unsigned val = pk_bf16(acc[2 * tp][r] * dvr, acc[2 * tp + 1][r] * dvr);
                    hsb[(size_t)row * 64 + tp * 16 + (lane & 15)] = val;
                }
            }
        }
    }
}

// ---------------- agg1: slot-elementwise; slot s holds features (32*(s>>4)+(s&15), +16) ----
__global__ __launch_bounds__(256) void agg1_kernel(const unsigned* __restrict__ hsb,
                                                   const int* __restrict__ row_ptr,
                                                   const int* __restrict__ col,
                                                   const float* __restrict__ dinv,
                                                   const float* __restrict__ b1,
                                                   unsigned* __restrict__ h1b) {
    int wave = (blockIdx.x * blockDim.x + threadIdx.x) >> 6;
    int lane = threadIdx.x & 63;
    int nwaves = (gridDim.x * blockDim.x) >> 6;
    int f0 = 32 * (lane >> 4) + (lane & 15);
    float bx = b1[f0];
    float by = b1[f0 + 16];
    for (int i = wave; i < NN; i += nwaves) {
        float2 t = upk_bf16(hsb[(size_t)i * 64 + lane]);  // self term
        float ax = t.x, ay = t.y;
        int e = row_ptr[i], s1 = row_ptr[i + 1];
        for (; e + 4 <= s1; e += 4) {
            int sa = col[e + 0], sb = col[e + 1], sc = col[e + 2], sd = col[e + 3];
            unsigned ua = hsb[(size_t)sa * 64 + lane];
            unsigned ub = hsb[(size_t)sb * 64 + lane];
            unsigned uc = hsb[(size_t)sc * 64 + lane];
            unsigned ud = hsb[(size_t)sd * 64 + lane];
            float2 va = upk_bf16(ua), vb = upk_bf16(ub), vc = upk_bf16(uc), vd = upk_bf16(ud);
            ax += va.x + vb.x + vc.x + vd.x;
            ay += va.y + vb.y + vc.y + vd.y;
        }
        for (; e < s1; ++e) {
            float2 v = upk_bf16(hsb[(size_t)col[e] * 64 + lane]);
            ax += v.x;
            ay += v.y;
        }
        float dvv = dinv[i];
        float ox = fmaxf(fmaf(ax, dvv, bx), 0.f);
        float oy = fmaxf(fmaf(ay, dvv, by), 0.f);
        h1b[(size_t)i * 64 + lane] = pk_bf16(ox, oy);
    }
}

// ---------------- GEMM2: hs2b = bf16((h1 @ W2) * dinv[row]) ----------------
// h1b slots are permuted; compensate via W2 row remap during LDS staging.
__global__ __launch_bounds__(256) void gemm2_kernel(const unsigned* __restrict__ h1b,
                                                    const float* __restrict__ W2,
                                                    const float* __restrict__ dinv,
                                                    unsigned* __restrict__ hs2b) {
    __shared__ float wlds[HID][64];   // 32KB zero-padded, k-index in PERMUTED slot order
    __shared__ float xlds[64][HID];   // 32KB
    int tid = threadIdx.x;
    for (int i = tid; i < HID * 64; i += 256) {
        int kk = i / 64, c = i % 64;
        int s = kk >> 1, half = kk & 1;
        int realk = 32 * (s >> 4) + 16 * half + (s & 15);
        wlds[kk][c] = (c < NCLS) ? W2[realk * NCLS + c] : 0.f;
    }
    int ct = tid & 15;   // c0 = 4*ct (0..60)
    int rt = tid >> 4;   // 0..15 -> 64 rows
    int c0 = ct * 4;
    int nt = (NN + 63) / 64;
    for (int t = blockIdx.x; t < nt; t += gridDim.x) {
        int rowbase = t * 64;
        __syncthreads();
        for (int i = tid; i < 64 * 16; i += 256) {
            int r = i >> 4, q = i & 15;
            int row = rowbase + r;
            uint4 u = (row < NN) ? ((const uint4*)h1b)[(size_t)row * 16 + q]
                                 : make_uint4(0, 0, 0, 0);
            float2 g0 = upk_bf16(u.x), g1 = upk_bf16(u.y);
            float2 g2 = upk_bf16(u.z), g3 = upk_bf16(u.w);
            float* dp = &xlds[r][q * 8];
            ((float4*)dp)[0] = make_float4(g0.x, g0.y, g1.x, g1.y);
            ((float4*)dp)[1] = make_float4(g2.x, g2.y, g3.x, g3.y);
        }
        __syncthreads();
        float acc[4][4];
#pragma unroll
        for (int a = 0; a < 4; ++a)
#pragma unroll
            for (int b = 0; b < 4; ++b) acc[a][b] = 0.f;
        for (int k = 0; k < HID; k += 4) {
            float4 xv[4], wv[4];
#pragma unroll
            for (int a = 0; a < 4; ++a) xv[a] = *(const float4*)&xlds[rt * 4 + a][k];
#pragma unroll
            for (int kk = 0; kk < 4; ++kk) wv[kk] = *(const float4*)&wlds[k + kk][c0];
#pragma unroll
            for (int kk = 0; kk < 4; ++kk) {
                float4 w = wv[kk];
#pragma unroll
                for (int a = 0; a < 4; ++a) {
                    float xs = ((float*)&xv[a])[kk];
                    acc[a][0] = fmaf(xs, w.x, acc[a][0]);
                    acc[a][1] = fmaf(xs, w.y, acc[a][1]);
                    acc[a][2] = fmaf(xs, w.z, acc[a][2]);
                    acc[a][3] = fmaf(xs, w.w, acc[a][3]);
                }
            }
        }
        if (c0 < NCLS) {
#pragma unroll
            for (int a = 0; a < 4; ++a) {
                int row = rowbase + rt * 4 + a;
                if (row < NN) {
                    float dvv = dinv[row];
                    uint2 o = make_uint2(pk_bf16(acc[a][0] * dvv, acc[a][1] * dvv),
                                         pk_bf16(acc[a][2] * dvv, acc[a][3] * dvv));
                    *(uint2*)(hs2b + (size_t)row * 20 + ct * 2) = o;
                }
            }
        }
    }
}

// ---------------- agg2 + bias + log_softmax: 2 nodes per wave ----------------
// half h (32 lanes) owns node 2p+h; lanes 0..19 of each half hold class pairs.
__global__ __launch_bounds__(256) void agg2_kernel(const unsigned* __restrict__ hs2b,
                                                   const int* __restrict__ row_ptr,
                                                   const int* __restrict__ col,
                                                   const float* __restrict__ dinv,
                                                   const float* __restrict__ b2,
                                                   float* __restrict__ out) {
    int wave = (blockIdx.x * blockDim.x + threadIdx.x) >> 6;
    int half = (threadIdx.x >> 5) & 1;
    int l = threadIdx.x & 31;           // lane within half
    int nwaves = (gridDim.x * blockDim.x) >> 6;
    bool act = l < (NCLS / 2);
    float2 bb = act ? ((const float2*)b2)[l] : make_float2(0.f, 0.f);
    const int npairs = NN / 2;          // NN even
    for (int p = wave; p < npairs; p += nwaves) {
        int i = 2 * p + half;
        float ax = 0.f, ay = 0.f;
        if (act) {
            float2 t = upk_bf16(hs2b[(size_t)i * 20 + l]);  // self term
            ax = t.x; ay = t.y;
        }
        int e = row_ptr[i], s1 = row_ptr[i + 1];
        for (; e + 4 <= s1; e += 4) {
            int sa = col[e + 0], sb = col[e + 1], sc = col[e + 2], sd = col[e + 3];
            if (act) {
                float2 va = upk_bf16(hs2b[(size_t)sa * 20 + l]);
                float2 vb = upk_bf16(hs2b[(size_t)sb * 20 + l]);
                float2 vc = upk_bf16(hs2b[(size_t)sc * 20 + l]);
                float2 vd = upk_bf16(hs2b[(size_t)sd * 20 + l]);
                ax += va.x + vb.x + vc.x + vd.x;
                ay += va.y + vb.y + vc.y + vd.y;
            }
        }
        for (; e < s1; ++e) {
            int s = col[e];
            if (act) {
                float2 v = upk_bf16(hs2b[(size_t)s * 20 + l]);
                ax += v.x;
                ay += v.y;
            }
        }
        float dvv = dinv[i];
        float lx = fmaf(ax, dvv, bb.x);
        float ly = fmaf(ay, dvv, bb.y);
        float m = act ? fmaxf(lx, ly) : -INFINITY;
#pragma unroll
        for (int off = 16; off; off >>= 1) m = fmaxf(m, __shfl_xor(m, off, 32));
        float ssum = act ? (expf(lx - m) + expf(ly - m)) : 0.f;
#pragma unroll
        for (int off = 16; off; off >>= 1) ssum += __shfl_xor(ssum, off, 32);
        float ls = logf(ssum);
        if (act) {
            float2 o = make_float2(lx - m - ls, ly - m - ls);
            ((float2*)(out + (size_t)i * NCLS))[l] = o;
        }
    }
}

extern "C" void kernel_launch(void* const* d_in, const int* in_sizes, int n_in,
                              void* d_out, int out_size, void* d_ws, size_t ws_size,
                              hipStream_t stream) {
    const float* x = (const float*)d_in[0];
    const int* edge_index = (const int*)d_in[1];
    const float* W1 = (const float*)d_in[2];
    const float* b1 = (const float*)d_in[3];
    const float* W2 = (const float*)d_in[4];
    const float* b2 = (const float*)d_in[5];
    float* out = (float*)d_out;
    const int* src = edge_index;          // edge_index[0]
    const int* dst = edge_index + NE;     // edge_index[1]

    char* ws = (char*)d_ws;
    size_t off = 0;
    auto alloc = [&](size_t bytes) -> void* {
        void* p = (void*)(ws + off);
        off += (bytes + 255) & ~(size_t)255;
        return p;
    };
    int* bcnt = (int*)alloc((size_t)NC * 4);
    int* bbase = (int*)alloc((size_t)(NC + 1) * 4);
    int* bcur = (int*)alloc((size_t)NC * 4);
    int* row_ptr = (int*)alloc((size_t)(NN + 1) * 4);
    int* col = (int*)alloc((size_t)NE * 4);
    float* dinv = (float*)alloc((size_t)NN * 4);
    unsigned* hsb = (unsigned*)alloc((size_t)NN * 64 * 4);   // bf16x2 packed [NN][64] (slot-permuted)
    unsigned* h1b = (unsigned*)alloc((size_t)NN * 64 * 4);   // bf16x2 packed [NN][64] (slot-permuted)
    unsigned* hs2b = (unsigned*)alloc((size_t)NN * 20 * 4);  // bf16x2 packed [NN][20]
    unsigned* staged = h1b;  // alias: staged fully consumed by build before agg1 writes h1b

    hipMemsetAsync(bcnt, 0, (size_t)NC * 4, stream);
    hipMemsetAsync(bcur, 0, (size_t)NC * 4, stream);

    bhist_kernel<<<NCHUNK, 256, 0, stream>>>(dst, bcnt);
    bscan_kernel<<<1, 256, 0, stream>>>(bcnt, bbase);
    part_kernel<<<NCHUNK, 256, 0, stream>>>(src, dst, bbase, bcur, staged);
    build_kernel<<<NC, 512, 0, stream>>>(staged, bbase, row_ptr, dinv, col);
    gemm1_kernel<<<768, 256, 0, stream>>>(x, W1, dinv, hsb);
    agg1_kernel<<<2048, 256, 0, stream>>>(hsb, row_ptr, col, dinv, b1, h1b);
    gemm2_kernel<<<512, 256, 0, stream>>>(h1b, W2, dinv, hs2b);
    agg2_kernel<<<2048, 256, 0, stream>>>(hs2b, row_ptr, col, dinv, b2, out);
}

// Round 16
// 309.834 us; speedup vs baseline: 1.6682x; 1.1014x over previous
//
#include <hip/hip_runtime.h>
#include <cmath>

#define NN 100000
#define NE 1600000
#define FIN 128
#define HID 128
#define NCLS 40

#define CSH 9                 // coarse bucket = dst >> 9 (512 nodes)
#define CNODES 512
#define NC 196                // ceil(100000/512)
#define CHUNK 8192
#define NCHUNK ((NE + CHUNK - 1) / CHUNK)   // 196

#define KP 136                // padded LDS row length (bf16)

typedef __attribute__((ext_vector_type(8))) short bf16x8;
typedef __attribute__((ext_vector_type(4))) float f32x4;
typedef __attribute__((ext_vector_type(2))) float f32x2;

// ---- packed bf16 helpers (RNE) ----
__device__ __forceinline__ unsigned pk_bf16(float a, float b) {
    unsigned ua = __float_as_uint(a);
    unsigned ub = __float_as_uint(b);
    ua += 0x7FFFu + ((ua >> 16) & 1u);
    ub += 0x7FFFu + ((ub >> 16) & 1u);
    return (ua >> 16) | (ub & 0xFFFF0000u);
}
__device__ __forceinline__ float2 upk_bf16(unsigned u) {
    return make_float2(__uint_as_float(u << 16), __uint_as_float(u & 0xFFFF0000u));
}
__device__ __forceinline__ unsigned short bf16r(float f) {
    unsigned u = __float_as_uint(f);
    u += 0x7FFFu + ((u >> 16) & 1u);
    return (unsigned short)(u >> 16);
}

// ---------------- CSR build v3 (unchanged) ----------------

__global__ __launch_bounds__(256) void bhist_kernel(const int* __restrict__ dst,
                                                    int* __restrict__ bcnt) {
    __shared__ int h[NC];
    int tid = threadIdx.x;
    if (tid < NC) h[tid] = 0;
    __syncthreads();
    int base = blockIdx.x * CHUNK;
    int end = min(base + CHUNK, NE);
    for (int e = base + tid; e < end; e += 256) atomicAdd(&h[dst[e] >> CSH], 1);
    __syncthreads();
    if (tid < NC) {
        int v = h[tid];
        if (v) atomicAdd(&bcnt[tid], v);
    }
}

__global__ __launch_bounds__(256) void bscan_kernel(const int* __restrict__ bcnt,
                                                    int* __restrict__ bbase) {
    __shared__ int t[256];
    int tid = threadIdx.x;
    int v = (tid < NC) ? bcnt[tid] : 0;
    t[tid] = v;
    __syncthreads();
    for (int off = 1; off < 256; off <<= 1) {
        int a = (tid >= off) ? t[tid - off] : 0;
        __syncthreads();
        t[tid] += a;
        __syncthreads();
    }
    if (tid < NC) bbase[tid] = t[tid] - v;
    if (tid == 0) bbase[NC] = NE;
}

__global__ __launch_bounds__(256) void part_kernel(const int* __restrict__ src,
                                                   const int* __restrict__ dst,
                                                   const int* __restrict__ bbase,
                                                   int* __restrict__ bcur,
                                                   unsigned* __restrict__ staged) {
    __shared__ int cnt[NC], lofs[NC], gofs[NC], lcur[NC];
    __shared__ int tt[256];
    __shared__ unsigned sbuf[CHUNK];         // 32KB
    __shared__ unsigned short bof[CHUNK];    // 16KB
    int tid = threadIdx.x;
    if (tid < NC) { cnt[tid] = 0; lcur[tid] = 0; }
    __syncthreads();
    int base = blockIdx.x * CHUNK;
    int end = min(base + CHUNK, NE);
    for (int e = base + tid; e < end; e += 256) atomicAdd(&cnt[dst[e] >> CSH], 1);
    __syncthreads();
    int v = (tid < NC) ? cnt[tid] : 0;
    tt[tid] = v;
    __syncthreads();
    for (int off = 1; off < 256; off <<= 1) {
        int a = (tid >= off) ? tt[tid - off] : 0;
        __syncthreads();
        tt[tid] += a;
        __syncthreads();
    }
    if (tid < NC) {
        lofs[tid] = tt[tid] - v;
        if (v) gofs[tid] = atomicAdd(&bcur[tid], v);
    }
    __syncthreads();
    for (int e = base + tid; e < end; e += 256) {
        int d = dst[e];
        int b = d >> CSH;
        int p = atomicAdd(&lcur[b], 1);
        int pos = lofs[b] + p;
        sbuf[pos] = ((unsigned)src[e] << CSH) | (unsigned)(d & (CNODES - 1));
        bof[pos] = (unsigned short)b;
    }
    __syncthreads();
    int n = end - base;
    for (int i = tid; i < n; i += 256) {
        int b = bof[i];
        staged[bbase[b] + gofs[b] + (i - lofs[b])] = sbuf[i];
    }
}

__global__ __launch_bounds__(512) void build_kernel(const unsigned* __restrict__ staged,
                                                    const int* __restrict__ bbase,
                                                    int* __restrict__ row_ptr,
                                                    float* __restrict__ dinv,
                                                    int* __restrict__ col) {
    __shared__ int deg[CNODES], cur[CNODES], tt[CNODES];
    int tid = threadIdx.x;
    int b = blockIdx.x;
    int nbase = b << CSH;
    int ebeg = bbase[b], eend = bbase[b + 1];
    int cnt_e = eend - ebeg;
    deg[tid] = 0;
    __syncthreads();
    for (int i = tid; i < cnt_e; i += 512) atomicAdd(&deg[staged[ebeg + i] & (CNODES - 1)], 1);
    __syncthreads();
    int v = deg[tid];
    tt[tid] = v;
    __syncthreads();
    for (int off = 1; off < 512; off <<= 1) {
        int a = (tid >= off) ? tt[tid - off] : 0;
        __syncthreads();
        tt[tid] += a;
        __syncthreads();
    }
    int ex = tt[tid] - v;
    cur[tid] = ex;
    int node = nbase + tid;
    if (node < NN) {
        row_ptr[node] = ebeg + ex;
        dinv[node] = rsqrtf((float)(v + 1));  // +1 self-loop
    }
    if (b == NC - 1 && tid == 0) row_ptr[NN] = NE;
    __syncthreads();
    for (int i = tid; i < cnt_e; i += 512) {
        unsigned u = staged[ebeg + i];
        int p = atomicAdd(&cur[u & (CNODES - 1)], 1);
        col[ebeg + p] = (int)(u >> CSH);
    }
}

// ---------------- GEMM1 (MFMA bf16): hsb = fp8((x @ W1) * dinv[row]) ----------------
// hsb row = 32 dwords of 4x fp8-e4m3. Slot s<16: features {s,s+16,s+32,s+48};
// slot 16+c: {64+c,80+c,96+c,112+c}.
__global__ __launch_bounds__(256) void gemm1_kernel(const float* __restrict__ x,
                                                    const float* __restrict__ W1,
                                                    const float* __restrict__ dinv,
                                                    unsigned* __restrict__ hsb) {
    __shared__ unsigned short wt[HID][KP];   // W1^T bf16 [n][k]
    __shared__ unsigned short xt[64][KP];    // x tile bf16 [r][k]
    __shared__ float dv[64];
    int tid = threadIdx.x;
    int lane = tid & 63;
    int w = tid >> 6;
    for (int i = tid; i < FIN * 32; i += 256) {
        int k = i >> 5, n4 = i & 31;
        float4 v = ((const float4*)W1)[k * 32 + n4];
        wt[n4 * 4 + 0][k] = bf16r(v.x);
        wt[n4 * 4 + 1][k] = bf16r(v.y);
        wt[n4 * 4 + 2][k] = bf16r(v.z);
        wt[n4 * 4 + 3][k] = bf16r(v.w);
    }
    int nt = (NN + 63) / 64;
    for (int t = blockIdx.x; t < nt; t += gridDim.x) {
        int rowbase = t * 64;
        __syncthreads();
        for (int i = tid; i < 64 * 32; i += 256) {
            int r = i >> 5, seg = i & 31;
            int row = rowbase + r;
            float4 v = (row < NN) ? ((const float4*)x)[(size_t)row * 32 + seg]
                                  : make_float4(0.f, 0.f, 0.f, 0.f);
            xt[r][seg * 4 + 0] = bf16r(v.x);
            xt[r][seg * 4 + 1] = bf16r(v.y);
            xt[r][seg * 4 + 2] = bf16r(v.z);
            xt[r][seg * 4 + 3] = bf16r(v.w);
        }
        if (tid < 64) {
            int row = rowbase + tid;
            dv[tid] = (row < NN) ? dinv[row] : 1.0f;
        }
        __syncthreads();
        f32x4 acc[8];
#pragma unroll
        for (int c = 0; c < 8; ++c) acc[c] = (f32x4){0.f, 0.f, 0.f, 0.f};
        int arow = w * 16 + (lane & 15);
        int koff = (lane >> 4) * 8;
#pragma unroll
        for (int k0 = 0; k0 < FIN; k0 += 32) {
            bf16x8 av = *(const bf16x8*)&xt[arow][k0 + koff];
#pragma unroll
            for (int ct = 0; ct < 8; ++ct) {
                bf16x8 bv = *(const bf16x8*)&wt[ct * 16 + (lane & 15)][k0 + koff];
                acc[ct] = __builtin_amdgcn_mfma_f32_16x16x32_bf16(av, bv, acc[ct], 0, 0, 0);
            }
        }
        int rl0 = w * 16 + (lane >> 4) * 4;
        int c = lane & 15;
#pragma unroll
        for (int r = 0; r < 4; ++r) {
            int row = rowbase + rl0 + r;
            if (row < NN) {
                float dvr = dv[rl0 + r];
                int w0 = __builtin_amdgcn_cvt_pk_fp8_f32(acc[0][r] * dvr, acc[1][r] * dvr, 0, false);
                w0 = __builtin_amdgcn_cvt_pk_fp8_f32(acc[2][r] * dvr, acc[3][r] * dvr, w0, true);
                int w1 = __builtin_amdgcn_cvt_pk_fp8_f32(acc[4][r] * dvr, acc[5][r] * dvr, 0, false);
                w1 = __builtin_amdgcn_cvt_pk_fp8_f32(acc[6][r] * dvr, acc[7][r] * dvr, w1, true);
                hsb[(size_t)row * 32 + c] = (unsigned)w0;
                hsb[(size_t)row * 32 + 16 + c] = (unsigned)w1;
            }
        }
    }
}

// ---------------- agg1: 2 nodes/wave; lane l owns hsb dword slot l (4 features) ------
// features of slot l: base = 64*(l>>4)+(l&15); {base, base+16, base+32, base+48}
// h1b dword d: l=d&31, hi=d>>5, half per bf16 pair -> feature 64*(l>>4)+(l&15)+32*hi+16*half
__global__ __launch_bounds__(256) void agg1_kernel(const unsigned* __restrict__ hsb,
                                                   const int* __restrict__ row_ptr,
                                                   const int* __restrict__ col,
                                                   const float* __restrict__ dinv,
                                                   const float* __restrict__ b1,
                                                   unsigned* __restrict__ h1b) {
    int wave = (blockIdx.x * blockDim.x + threadIdx.x) >> 6;
    int half = (threadIdx.x >> 5) & 1;
    int l = threadIdx.x & 31;
    int nwaves = (gridDim.x * blockDim.x) >> 6;
    int base = 64 * (l >> 4) + (l & 15);
    float bb0 = b1[base], bb1 = b1[base + 16], bb2 = b1[base + 32], bb3 = b1[base + 48];
    const int npairs = NN / 2;  // NN even
    for (int p = wave; p < npairs; p += nwaves) {
        int i = 2 * p + half;
        unsigned us = hsb[(size_t)i * 32 + l];  // self term
        f32x2 slo = __builtin_amdgcn_cvt_pk_f32_fp8(us, false);
        f32x2 shi = __builtin_amdgcn_cvt_pk_f32_fp8(us, true);
        float a0 = slo[0], a1 = slo[1], a2 = shi[0], a3 = shi[1];
        int e = row_ptr[i], s1 = row_ptr[i + 1];
        for (; e + 4 <= s1; e += 4) {
            unsigned ua = hsb[(size_t)col[e + 0] * 32 + l];
            unsigned ub = hsb[(size_t)col[e + 1] * 32 + l];
            unsigned uc = hsb[(size_t)col[e + 2] * 32 + l];
            unsigned ud = hsb[(size_t)col[e + 3] * 32 + l];
            f32x2 la = __builtin_amdgcn_cvt_pk_f32_fp8(ua, false);
            f32x2 ha = __builtin_amdgcn_cvt_pk_f32_fp8(ua, true);
            f32x2 lb = __builtin_amdgcn_cvt_pk_f32_fp8(ub, false);
            f32x2 hb = __builtin_amdgcn_cvt_pk_f32_fp8(ub, true);
            f32x2 lc = __builtin_amdgcn_cvt_pk_f32_fp8(uc, false);
            f32x2 hc = __builtin_amdgcn_cvt_pk_f32_fp8(uc, true);
            f32x2 ld = __builtin_amdgcn_cvt_pk_f32_fp8(ud, false);
            f32x2 hd = __builtin_amdgcn_cvt_pk_f32_fp8(ud, true);
            a0 += la[0] + lb[0] + lc[0] + ld[0];
            a1 += la[1] + lb[1] + lc[1] + ld[1];
            a2 += ha[0] + hb[0] + hc[0] + hd[0];
            a3 += ha[1] + hb[1] + hc[1] + hd[1];
        }
        for (; e < s1; ++e) {
            unsigned u = hsb[(size_t)col[e] * 32 + l];
            f32x2 lo = __builtin_amdgcn_cvt_pk_f32_fp8(u, false);
            f32x2 hi = __builtin_amdgcn_cvt_pk_f32_fp8(u, true);
            a0 += lo[0];
            a1 += lo[1];
            a2 += hi[0];
            a3 += hi[1];
        }
        float dvv = dinv[i];
        float o0 = fmaxf(fmaf(a0, dvv, bb0), 0.f);
        float o1 = fmaxf(fmaf(a1, dvv, bb1), 0.f);
        float o2 = fmaxf(fmaf(a2, dvv, bb2), 0.f);
        float o3 = fmaxf(fmaf(a3, dvv, bb3), 0.f);
        h1b[(size_t)i * 64 + l] = pk_bf16(o0, o1);
        h1b[(size_t)i * 64 + 32 + l] = pk_bf16(o2, o3);
    }
}

// ---------------- GEMM2: hs2b = bf16((h1 @ W2) * dinv[row]) ----------------
// h1b slot layout: dword d -> l=d&31, hi=d>>5; bf16 half -> realk = 64*(l>>4)+(l&15)+32*hi+16*half
__global__ __launch_bounds__(256) void gemm2_kernel(const unsigned* __restrict__ h1b,
                                                    const float* __restrict__ W2,
                                                    const float* __restrict__ dinv,
                                                    unsigned* __restrict__ hs2b) {
    __shared__ float wlds[HID][64];   // 32KB zero-padded, k-index in PERMUTED slot order
    __shared__ float xlds[64][HID];   // 32KB
    int tid = threadIdx.x;
    for (int i = tid; i < HID * 64; i += 256) {
        int kk = i / 64, c = i % 64;
        int d = kk >> 1, hf = kk & 1;
        int l = d & 31, hi2 = d >> 5;
        int realk = 64 * (l >> 4) + (l & 15) + 32 * hi2 + 16 * hf;
        wlds[kk][c] = (c < NCLS) ? W2[realk * NCLS + c] : 0.f;
    }
    int ct = tid & 15;   // c0 = 4*ct (0..60)
    int rt = tid >> 4;   // 0..15 -> 64 rows
    int c0 = ct * 4;
    int nt = (NN + 63) / 64;
    for (int t = blockIdx.x; t < nt; t += gridDim.x) {
        int rowbase = t * 64;
        __syncthreads();
        for (int i = tid; i < 64 * 16; i += 256) {
            int r = i >> 4, q = i & 15;
            int row = rowbase + r;
            uint4 u = (row < NN) ? ((const uint4*)h1b)[(size_t)row * 16 + q]
                                 : make_uint4(0, 0, 0, 0);
            float2 g0 = upk_bf16(u.x), g1 = upk_bf16(u.y);
            float2 g2 = upk_bf16(u.z), g3 = upk_bf16(u.w);
            float* dp = &xlds[r][q * 8];
            ((float4*)dp)[0] = make_float4(g0.x, g0.y, g1.x, g1.y);
            ((float4*)dp)[1] = make_float4(g2.x, g2.y, g3.x, g3.y);
        }
        __syncthreads();
        float acc[4][4];
#pragma unroll
        for (int a = 0; a < 4; ++a)
#pragma unroll
            for (int b = 0; b < 4; ++b) acc[a][b] = 0.f;
        for (int k = 0; k < HID; k += 4) {
            float4 xv[4], wv[4];
#pragma unroll
            for (int a = 0; a < 4; ++a) xv[a] = *(const float4*)&xlds[rt * 4 + a][k];
#pragma unroll
            for (int kk = 0; kk < 4; ++kk) wv[kk] = *(const float4*)&wlds[k + kk][c0];
#pragma unroll
            for (int kk = 0; kk < 4; ++kk) {
                float4 w = wv[kk];
#pragma unroll
                for (int a = 0; a < 4; ++a) {
                    float xs = ((float*)&xv[a])[kk];
                    acc[a][0] = fmaf(xs, w.x, acc[a][0]);
                    acc[a][1] = fmaf(xs, w.y, acc[a][1]);
                    acc[a][2] = fmaf(xs, w.z, acc[a][2]);
                    acc[a][3] = fmaf(xs, w.w, acc[a][3]);
                }
            }
        }
        if (c0 < NCLS) {
#pragma unroll
            for (int a = 0; a < 4; ++a) {
                int row = rowbase + rt * 4 + a;
                if (row < NN) {
                    float dvv = dinv[row];
                    uint2 o = make_uint2(pk_bf16(acc[a][0] * dvv, acc[a][1] * dvv),
                                         pk_bf16(acc[a][2] * dvv, acc[a][3] * dvv));
                    *(uint2*)(hs2b + (size_t)row * 20 + ct * 2) = o;
                }
            }
        }
    }
}

// ---------------- agg2 + bias + log_softmax: 2 nodes per wave (unchanged) -----------
__global__ __launch_bounds__(256) void agg2_kernel(const unsigned* __restrict__ hs2b,
                                                   const int* __restrict__ row_ptr,
                                                   const int* __restrict__ col,
                                                   const float* __restrict__ dinv,
                                                   const float* __restrict__ b2,
                                                   float* __restrict__ out) {
    int wave = (blockIdx.x * blockDim.x + threadIdx.x) >> 6;
    int half = (threadIdx.x >> 5) & 1;
    int l = threadIdx.x & 31;           // lane within half
    int nwaves = (gridDim.x * blockDim.x) >> 6;
    bool act = l < (NCLS / 2);
    float2 bb = act ? ((const float2*)b2)[l] : make_float2(0.f, 0.f);
    const int npairs = NN / 2;          // NN even
    for (int p = wave; p < npairs; p += nwaves) {
        int i = 2 * p + half;
        float ax = 0.f, ay = 0.f;
        if (act) {
            float2 t = upk_bf16(hs2b[(size_t)i * 20 + l]);  // self term
            ax = t.x; ay = t.y;
        }
        int e = row_ptr[i], s1 = row_ptr[i + 1];
        for (; e + 4 <= s1; e += 4) {
            int sa = col[e + 0], sb = col[e + 1], sc = col[e + 2], sd = col[e + 3];
            if (act) {
                float2 va = upk_bf16(hs2b[(size_t)sa * 20 + l]);
                float2 vb = upk_bf16(hs2b[(size_t)sb * 20 + l]);
                float2 vc = upk_bf16(hs2b[(size_t)sc * 20 + l]);
                float2 vd = upk_bf16(hs2b[(size_t)sd * 20 + l]);
                ax += va.x + vb.x + vc.x + vd.x;
                ay += va.y + vb.y + vc.y + vd.y;
            }
        }
        for (; e < s1; ++e) {
            int s = col[e];
            if (act) {
                float2 v = upk_bf16(hs2b[(size_t)s * 20 + l]);
                ax += v.x;
                ay += v.y;
            }
        }
        float dvv = dinv[i];
        float lx = fmaf(ax, dvv, bb.x);
        float ly = fmaf(ay, dvv, bb.y);
        float m = act ? fmaxf(lx, ly) : -INFINITY;
#pragma unroll
        for (int off = 16; off; off >>= 1) m = fmaxf(m, __shfl_xor(m, off, 32));
        float ssum = act ? (expf(lx - m) + expf(ly - m)) : 0.f;
#pragma unroll
        for (int off = 16; off; off >>= 1) ssum += __shfl_xor(ssum, off, 32);
        float ls = logf(ssum);
        if (act) {
            float2 o = make_float2(lx - m - ls, ly - m - ls);
            ((float2*)(out + (size_t)i * NCLS))[l] = o;
        }
    }
}

extern "C" void kernel_launch(void* const* d_in, const int* in_sizes, int n_in,
                              void* d_out, int out_size, void* d_ws, size_t ws_size,
                              hipStream_t stream) {
    const float* x = (const float*)d_in[0];
    const int* edge_index = (const int*)d_in[1];
    const float* W1 = (const float*)d_in[2];
    const float* b1 = (const float*)d_in[3];
    const float* W2 = (const float*)d_in[4];
    const float* b2 = (const float*)d_in[5];
    float* out = (float*)d_out;
    const int* src = edge_index;          // edge_index[0]
    const int* dst = edge_index + NE;     // edge_index[1]

    char* ws = (char*)d_ws;
    size_t off = 0;
    auto alloc = [&](size_t bytes) -> void* {
        void* p = (void*)(ws + off);
        off += (bytes + 255) & ~(size_t)255;
        return p;
    };
    int* bcnt = (int*)alloc((size_t)NC * 4);
    int* bbase = (int*)alloc((size_t)(NC + 1) * 4);
    int* bcur = (int*)alloc((size_t)NC * 4);
    int* row_ptr = (int*)alloc((size_t)(NN + 1) * 4);
    int* col = (int*)alloc((size_t)NE * 4);
    float* dinv = (float*)alloc((size_t)NN * 4);
    unsigned* hsb = (unsigned*)alloc((size_t)NN * 32 * 4);   // fp8x4 packed [NN][32]
    unsigned* h1b = (unsigned*)alloc((size_t)NN * 64 * 4);   // bf16x2 packed [NN][64] (slot layout v2)
    unsigned* hs2b = (unsigned*)alloc((size_t)NN * 20 * 4);  // bf16x2 packed [NN][20]
    unsigned* staged = h1b;  // alias: staged fully consumed by build before agg1 writes h1b

    hipMemsetAsync(bcnt, 0, (size_t)NC * 4, stream);
    hipMemsetAsync(bcur, 0, (size_t)NC * 4, stream);

    bhist_kernel<<<NCHUNK, 256, 0, stream>>>(dst, bcnt);
    bscan_kernel<<<1, 256, 0, stream>>>(bcnt, bbase);
    part_kernel<<<NCHUNK, 256, 0, stream>>>(src, dst, bbase, bcur, staged);
    build_kernel<<<NC, 512, 0, stream>>>(staged, bbase, row_ptr, dinv, col);
    gemm1_kernel<<<768, 256, 0, stream>>>(x, W1, dinv, hsb);
    agg1_kernel<<<2048, 256, 0, stream>>>(hsb, row_ptr, col, dinv, b1, h1b);
    gemm2_kernel<<<512, 256, 0, stream>>>(h1b, W2, dinv, hs2b);
    agg2_kernel<<<2048, 256, 0, stream>>>(hs2b, row_ptr, col, dinv, b2, out);
}